// Round 27
// baseline (947.544 us; speedup 1.0000x reference)
//
#include <hip/hip_runtime.h>
#include <hip/hip_bf16.h>
#include <cstdint>
#include <cstddef>

#define KN 32
#define EPSV 1e-5f
#define BR 64
#define BO 64
#define BKK 16
#define ASTR 68   // fp32 LDS tile stride (dense fp32 kernel)
#define BKM 32    // mfma K-chunk
#define BKP 40    // bf16 LDS row stride in shorts (80B: 16B-aligned, bank-spread)

typedef float f32x4 __attribute__((ext_vector_type(4)));
typedef __bf16 bf16x8 __attribute__((ext_vector_type(8)));
typedef unsigned short ushort8 __attribute__((ext_vector_type(8)));

static inline int ceil_div(int a, int b) { return (a + b - 1) / b; }

__device__ __forceinline__ float b2f(unsigned short u) {
  union { float f; uint32_t i; } x;
  x.i = (uint32_t)u << 16;
  return x.f;
}

__device__ __forceinline__ unsigned short f2bu(float f) {
  __hip_bfloat16 h = __float2bfloat16(f);
  union { __hip_bfloat16 h; unsigned short u; } c;
  c.h = h;
  return c.u;
}

// ================= fp32 -> bf16 row-major W repack =================
__global__ void convw_kernel(const float* W, __hip_bfloat16* Wb, int wk, int colOff,
                             long long tot, int K) {
  long long i = (long long)blockIdx.x * blockDim.x + threadIdx.x;
  if (i >= tot) return;
  int o = (int)(i / K), c = (int)(i % K);
  Wb[i] = __float2bfloat16(W[(size_t)o * wk + colOff + c]);
}

// ================= wide (128-row) dense bf16-MFMA GEMM =================
// R17 tile + R21 XCD swizzle + R23 pipelined staging + R24 Ga/Gm LDS staging
// + R26 Ga/Gm register prefetch (latency hidden under the K-loop).
struct MdArgs {
  const float* Af; const unsigned short* Ab; int lda;
  const float* W; int wk; int colOff;
  const unsigned short* Wb;   // dense bf16 [O][K] repack (WBF16 path)
  float* outf; __hip_bfloat16* outb;
  __hip_bfloat16* outb2; int Oh;   // EP1 split store (fused Gf|Ga)
  float* partial; int numOt;
  const unsigned short* Ga; const float* Gm;
  const float* xyz; const float* ctr; const int* idx;
  int M, Ncur;
  int R, K, O;
};

template <int EP, bool ABF16, bool WBF16>
__global__ __launch_bounds__(256) void gemm_mdw(MdArgs g) {
  constexpr int SMEMB = (EP == 2) ? 20480 : (128 + 64) * BKP * 2;
  __shared__ __align__(16) char smemraw[SMEMB];
  __shared__ float nxs[128][3];
  __shared__ float waxs[64][3];
  __shared__ int grow[128];
  __hip_bfloat16* As = (__hip_bfloat16*)smemraw;        // [128][BKP]
  __hip_bfloat16* Ws = As + 128 * BKP;                  // [64][BKP]
  const int tid = threadIdx.x;
  const int lane = tid & 63, w = tid >> 6;
  // XCD-aware decode: per-XCD contiguous rt-slab, ot fastest within the slab.
  const int cpx = gridDim.x >> 3;
  const int s = (blockIdx.x & 7) * cpx + (blockIdx.x >> 3);
  const int rt = s / g.numOt;
  const int ot = s - rt * g.numOt;
  const int br0 = rt * 128, bo0 = ot * BO;

  ushort8 rGa[4];
  float gmv;
  if constexpr (EP == 2) {
    if (tid < 128) {
      int r = br0 + tid;
      int bm = r >> 5;
      int b = bm / g.M;
      int n = g.idx[(size_t)bm * KN + (r & (KN - 1))];
      int nb = b * g.Ncur + n;
      grow[tid] = nb;
      nxs[tid][0] = g.xyz[(size_t)nb * 3 + 0] - g.ctr[(size_t)bm * 3 + 0];
      nxs[tid][1] = g.xyz[(size_t)nb * 3 + 1] - g.ctr[(size_t)bm * 3 + 1];
      nxs[tid][2] = g.xyz[(size_t)nb * 3 + 2] - g.ctr[(size_t)bm * 3 + 2];
    } else if (tid < 192) {
      int o = tid - 128;
      waxs[o][0] = g.W[(size_t)(bo0 + o) * g.wk + 0];
      waxs[o][1] = g.W[(size_t)(bo0 + o) * g.wk + 1];
      waxs[o][2] = g.W[(size_t)(bo0 + o) * g.wk + 2];
    }
    __syncthreads();
    // prefetch gathered Ga tile + Gm row into regs; latency hides under K-loop
#pragma unroll
    for (int p = 0; p < 4; ++p) {
      int i = tid + p * 256;
      int rl = i >> 3, sg = (i & 7) * 8;
      rGa[p] = *(const ushort8*)(g.Ga + (size_t)grow[rl] * g.O + bo0 + sg);
    }
    gmv = g.Gm[(size_t)((br0 >> 5) + (tid >> 6)) * g.O + bo0 + (tid & 63)];
  }

  f32x4 acc[2][4] = {};
  const int arow0 = (w * 16 + (lane & 15)) * BKP + (lane >> 4) * 8;
  const int arow1 = arow0 + 64 * BKP;
  const int sr = tid >> 2;          // staging row (0..63; +64 for 2nd half)
  const int sc8 = (tid & 3) * 8;    // staging k-offset
  const int wr = tid >> 2;
  const int wkb = (tid & 3) * 8;
  const float* wrow = WBF16 ? nullptr : (g.W + (size_t)(bo0 + wr) * g.wk + g.colOff);

  // ---- prologue: load k0=0 chunk into registers ----
  ushort8 rA0, rA1, rW;
  if constexpr (ABF16) {
    rA0 = *(const ushort8*)(g.Ab + (size_t)(br0 + sr) * g.lda + sc8);
    rA1 = *(const ushort8*)(g.Ab + (size_t)(br0 + 64 + sr) * g.lda + sc8);
  } else {
    const float* ap0 = g.Af + (size_t)(br0 + sr) * g.lda + sc8;
    const float* ap1 = g.Af + (size_t)(br0 + 64 + sr) * g.lda + sc8;
#pragma unroll
    for (int e = 0; e < 8; ++e) { rA0[e] = f2bu(ap0[e]); rA1[e] = f2bu(ap1[e]); }
  }
  if constexpr (WBF16) {
    rW = *(const ushort8*)(g.Wb + (size_t)(bo0 + wr) * g.K + wkb);
  } else {
#pragma unroll
    for (int e = 0; e < 8; ++e) rW[e] = f2bu(wrow[wkb + e]);
  }

  for (int k0 = 0; k0 < g.K; k0 += BKM) {
    // ---- write current chunk to LDS ----
    *(ushort8*)((unsigned short*)As + sr * BKP + sc8) = rA0;
    *(ushort8*)((unsigned short*)As + (64 + sr) * BKP + sc8) = rA1;
    *(ushort8*)((unsigned short*)Ws + wr * BKP + wkb) = rW;
    __syncthreads();
    // ---- issue next chunk's loads (latency hidden under compute) ----
    ushort8 nA0, nA1, nW;
    const int k1 = k0 + BKM;
    if (k1 < g.K) {
      if constexpr (ABF16) {
        nA0 = *(const ushort8*)(g.Ab + (size_t)(br0 + sr) * g.lda + k1 + sc8);
        nA1 = *(const ushort8*)(g.Ab + (size_t)(br0 + 64 + sr) * g.lda + k1 + sc8);
      } else {
        const float* ap0 = g.Af + (size_t)(br0 + sr) * g.lda + k1 + sc8;
        const float* ap1 = g.Af + (size_t)(br0 + 64 + sr) * g.lda + k1 + sc8;
#pragma unroll
        for (int e = 0; e < 8; ++e) { nA0[e] = f2bu(ap0[e]); nA1[e] = f2bu(ap1[e]); }
      }
      if constexpr (WBF16) {
        nW = *(const ushort8*)(g.Wb + (size_t)(bo0 + wr) * g.K + k1 + wkb);
      } else {
#pragma unroll
        for (int e = 0; e < 8; ++e) nW[e] = f2bu(wrow[k1 + wkb + e]);
      }
    }
    // ---- compute ----
    bf16x8 av0 = *(const bf16x8*)(As + arow0);
    bf16x8 av1 = *(const bf16x8*)(As + arow1);
#pragma unroll
    for (int nf = 0; nf < 4; ++nf) {
      bf16x8 bv = *(const bf16x8*)(Ws + (nf * 16 + (lane & 15)) * BKP + (lane >> 4) * 8);
      acc[0][nf] = __builtin_amdgcn_mfma_f32_16x16x32_bf16(av0, bv, acc[0][nf], 0, 0, 0);
      acc[1][nf] = __builtin_amdgcn_mfma_f32_16x16x32_bf16(av1, bv, acc[1][nf], 0, 0, 0);
    }
    __syncthreads();
    rA0 = nA0; rA1 = nA1; rW = nW;
  }

  const int col0 = lane & 15;
  unsigned short* GaS = (unsigned short*)smemraw;       // EP2: [128][68] bf16
  float* GmS = (float*)(smemraw + 17408);               // EP2: [4][64] f32
  float* red0 = (EP == 2) ? (float*)(smemraw + 18432) : (float*)smemraw;
  float* red1 = red0 + 256;

  if constexpr (EP == 2) {
    // write prefetched Ga tile + Gm rows to LDS (no global latency here)
#pragma unroll
    for (int p = 0; p < 4; ++p) {
      int i = tid + p * 256;
      int rl = i >> 3, sg = (i & 7) * 8;
      *(ushort8*)(GaS + rl * 68 + sg) = rGa[p];
    }
    GmS[tid] = gmv;
    __syncthreads();
  }

#pragma unroll
  for (int rf = 0; rf < 2; ++rf) {
    const int rbase = rf * 64 + w * 16 + (lane >> 4) * 4;
    if constexpr (EP == 0) {
#pragma unroll
      for (int nf = 0; nf < 4; ++nf) {
        int o = bo0 + nf * 16 + col0;
#pragma unroll
        for (int e = 0; e < 4; ++e)
          g.outf[(size_t)(br0 + rbase + e) * g.O + o] = acc[rf][nf][e];
      }
    }
    if constexpr (EP == 1) {
#pragma unroll
      for (int nf = 0; nf < 4; ++nf) {
        int o = bo0 + nf * 16 + col0;
        __hip_bfloat16* dst;
        int oc, ostr;
        if (g.outb2) {
          ostr = g.Oh;
          if (o >= g.Oh) { dst = g.outb2; oc = o - g.Oh; }
          else { dst = g.outb; oc = o; }
        } else {
          dst = g.outb; oc = o; ostr = g.O;
        }
#pragma unroll
        for (int e = 0; e < 4; ++e)
          dst[(size_t)(br0 + rbase + e) * ostr + oc] = __float2bfloat16(acc[rf][nf][e]);
      }
    }
    if constexpr (EP == 2 || EP == 3) {
      float vals[4][4];
#pragma unroll
      for (int nf = 0; nf < 4; ++nf) {
        int ol = nf * 16 + col0;
        int o = bo0 + ol;
#pragma unroll
        for (int e = 0; e < 4; ++e) {
          int rl = rbase + e;
          float v = acc[rf][nf][e];
          if constexpr (EP == 2) {
            v += b2f(GaS[rl * 68 + ol]) +
                 nxs[rl][0] * waxs[ol][0] + nxs[rl][1] * waxs[ol][1] +
                 nxs[rl][2] * waxs[ol][2] - GmS[((rl >> 5) << 6) + ol];
          }
          vals[nf][e] = v;
          if constexpr (EP == 2)
            g.outb[(size_t)(br0 + rl) * g.O + o] = __float2bfloat16(v);
          else
            g.outf[(size_t)(br0 + rl) * g.O + o] = v;
        }
      }
#pragma unroll
      for (int nf = 0; nf < 4; ++nf) {
        float s0 = vals[nf][0] + vals[nf][1] + vals[nf][2] + vals[nf][3];
        float s1 = vals[nf][0] * vals[nf][0] + vals[nf][1] * vals[nf][1] +
                   vals[nf][2] * vals[nf][2] + vals[nf][3] * vals[nf][3];
        s0 += __shfl_xor(s0, 16); s0 += __shfl_xor(s0, 32);
        s1 += __shfl_xor(s1, 16); s1 += __shfl_xor(s1, 32);
        if ((lane >> 4) == 0) {
          red0[w * 64 + nf * 16 + lane] = s0;
          red1[w * 64 + nf * 16 + lane] = s1;
        }
      }
      __syncthreads();
      if (tid < 64) {
        float t0 = red0[tid] + red0[64 + tid] + red0[128 + tid] + red0[192 + tid];
        float t1 = red1[tid] + red1[64 + tid] + red1[128 + tid] + red1[192 + tid];
        size_t base = ((size_t)(rt * 2 + rf) * g.numOt + ot) * 128;
        g.partial[base + tid] = t0;
        g.partial[base + 64 + tid] = t1;
      }
      __syncthreads();
    }
  }
}

// ================= fp combine: fp_pre = Gf[nbr] + nx.Wfx, + partials =================
__global__ __launch_bounds__(256) void combine_fp_kernel(
    const unsigned short* Gf, const float* Wf, int wk,
    const float* xyz, const float* ctr, const int* idx,
    __hip_bfloat16* fpout, float* partial, int numOt, int M, int Ncur, int O) {
  __shared__ float tile[64][68];
  __shared__ float nxs[64][3];
  __shared__ float wfx[64][3];
  __shared__ int grow[64];
  int tid = threadIdx.x;
  int rt = blockIdx.x, ot = blockIdx.y;
  int br0 = rt * 64, bo0 = ot * 64;
  if (tid < 64) {
    int r = br0 + tid;
    int bm = r >> 5;
    int b = bm / M;
    int n = idx[(size_t)bm * KN + (r & (KN - 1))];
    int nb = b * Ncur + n;
    grow[tid] = nb;
    nxs[tid][0] = xyz[(size_t)nb * 3 + 0] - ctr[(size_t)bm * 3 + 0];
    nxs[tid][1] = xyz[(size_t)nb * 3 + 1] - ctr[(size_t)bm * 3 + 1];
    nxs[tid][2] = xyz[(size_t)nb * 3 + 2] - ctr[(size_t)bm * 3 + 2];
  } else if (tid < 128) {
    int o = tid - 64;
    wfx[o][0] = Wf[(size_t)(bo0 + o) * wk + 0];
    wfx[o][1] = Wf[(size_t)(bo0 + o) * wk + 1];
    wfx[o][2] = Wf[(size_t)(bo0 + o) * wk + 2];
  }
  __syncthreads();
  int rr = tid >> 2, os = (tid & 3) * 16;
  const unsigned short* gr = Gf + (size_t)grow[rr] * O + bo0 + os;
  ushort8 v0 = *(const ushort8*)gr;
  ushort8 v1 = *(const ushort8*)(gr + 8);
  __hip_bfloat16* outp = fpout + (size_t)(br0 + rr) * O + bo0 + os;
  float nx0 = nxs[rr][0], nx1 = nxs[rr][1], nx2 = nxs[rr][2];
#pragma unroll
  for (int i = 0; i < 16; ++i) {
    float gv = b2f(i < 8 ? v0[i] : v1[i - 8]);
    int o = os + i;
    float val = gv + nx0 * wfx[o][0] + nx1 * wfx[o][1] + nx2 * wfx[o][2];
    tile[rr][o] = val;
    outp[i] = __float2bfloat16(val);
  }
  __syncthreads();
  if (tid < 64) {
    float s = 0.f, s2 = 0.f;
#pragma unroll 4
    for (int r2 = 0; r2 < 64; ++r2) {
      float v = tile[r2][tid];
      s += v; s2 += v * v;
    }
    size_t base = ((size_t)rt * numOt + ot) * 128;
    partial[base + tid] = s;
    partial[base + 64 + tid] = s2;
  }
}

// ================= fused bn+relu (in-place) + k-mean for fp buffer =================
// 256 threads = 4 bm-slabs per block (one per 64-lane group) for occupancy.
__global__ __launch_bounds__(256) void bn_fpmean_kernel(__hip_bfloat16* fp, const float2* stats2,
                                                        __hip_bfloat16* outm, int O) {
  int bm = blockIdx.x * 4 + (threadIdx.x >> 6);
  int o = blockIdx.y * 64 + (threadIdx.x & 63);
  float2 st = stats2[o];
  __hip_bfloat16* p = fp + (size_t)bm * KN * O + o;
  float s = 0.f;
#pragma unroll
  for (int kk = 0; kk < KN; ++kk) {
    float v = __bfloat162float(p[(size_t)kk * O]);
    float y = fmaxf((v - st.x) * st.y, 0.f);
    __hip_bfloat16 yb = __float2bfloat16(y);
    p[(size_t)kk * O] = yb;
    s += __bfloat162float(yb);
  }
  outm[(size_t)bm * O + o] = __float2bfloat16(s * (1.f / KN));
}

// ================= apply: bn+relu+softmax+weighted sum =================
// 256 threads = 4 bm per block (one per 64-lane group) for occupancy.
__global__ __launch_bounds__(256) void apply_lite_kernel(const __hip_bfloat16* alpha,
                                                         const __hip_bfloat16* fp,
                                                         const float2* stats2, float* fout, int O) {
  int bm = blockIdx.x * 4 + (threadIdx.x >> 6);
  int o = blockIdx.y * 64 + (threadIdx.x & 63);
  float2 st = stats2[o];
  size_t base = (size_t)bm * KN * O + o;
  float a[KN];
  float mx = -3.4e38f;
#pragma unroll
  for (int kk = 0; kk < KN; ++kk) {
    float v = fmaxf((__bfloat162float(alpha[base + (size_t)kk * O]) - st.x) * st.y, 0.f);
    a[kk] = v; mx = fmaxf(mx, v);
  }
  float s = 0.f;
#pragma unroll
  for (int kk = 0; kk < KN; ++kk) { float e = expf(a[kk] - mx); a[kk] = e; s += e; }
  float acc = 0.f;
#pragma unroll
  for (int kk = 0; kk < KN; ++kk) acc += a[kk] * __bfloat162float(fp[base + (size_t)kk * O]);
  fout[(size_t)bm * O + o] = acc / s;
}

// ================= fp32 dense GEMM (SPFE / head2) =================
struct GemmArgs {
  const float* A; const float* W; const float* bias;
  float* out; __hip_bfloat16* outb;
  float* partial; const float2* stats2; float* fout;
  const __hip_bfloat16* fpb; const float* fpmean;
  const float* xyz; const float* feat; const float* ctr; const int* idx; const float* bmean;
  int R, K, O, numOt, M, Cf, Of, Ncur;
};

template <int EMODE, int MODE>
__global__ __launch_bounds__(256) void gemm_dense(GemmArgs g) {
  __shared__ float smem[2 * BKK * ASTR];
  float* As = smem;
  float* Ws = smem + BKK * ASTR;
  const int tid = threadIdx.x;
  const int tr = tid >> 4, tc = tid & 15;
  const int rt = blockIdx.x, ot = blockIdx.y;
  const int br0 = rt * BR, bo0 = ot * BO;
  float acc[4][4] = {};
  for (int k0 = 0; k0 < g.K; k0 += BKK) {
    for (int i = tid; i < BR * BKK; i += 256) {
      int rr = i >> 4, cc = i & 15;
      int c = k0 + cc;
      float v = 0.f;
      if (c < g.K) {
        if constexpr (MODE == 0) {
          v = g.A[(size_t)(br0 + rr) * g.K + c];
        } else {
          int r = br0 + rr;
          int b = r / g.Ncur, n = r - b * g.Ncur;
          if (c < 3) v = g.xyz[((size_t)b * g.Ncur + n) * 3 + c];
          else if (c < 6) v = g.xyz[((size_t)b * g.Ncur + n) * 3 + (c - 3)] - g.bmean[b * 3 + (c - 3)];
        }
      }
      As[cc * ASTR + rr] = v;
    }
    for (int i = tid; i < BO * BKK; i += 256) {
      int oo = i >> 4, cc = i & 15;
      int o = bo0 + oo, c = k0 + cc;
      Ws[cc * ASTR + oo] = (o < g.O && c < g.K) ? g.W[(size_t)o * g.K + c] : 0.f;
    }
    __syncthreads();
#pragma unroll
    for (int kk = 0; kk < BKK; ++kk) {
      float a0[4], w0[4];
#pragma unroll
      for (int i = 0; i < 4; ++i) a0[i] = As[kk * ASTR + tr * 4 + i];
#pragma unroll
      for (int j = 0; j < 4; ++j) w0[j] = Ws[kk * ASTR + tc * 4 + j];
#pragma unroll
      for (int i = 0; i < 4; ++i)
#pragma unroll
        for (int j = 0; j < 4; ++j) acc[i][j] += a0[i] * w0[j];
    }
    __syncthreads();
  }
#pragma unroll
  for (int i = 0; i < 4; ++i) {
    int r = br0 + tr * 4 + i;
    if (r >= g.R) continue;
#pragma unroll
    for (int j = 0; j < 4; ++j) {
      int o = bo0 + tc * 4 + j;
      if (o >= g.O) continue;
      float v = acc[i][j];
      if (EMODE == 0 && g.bias) v += g.bias[o];
      g.out[(size_t)r * g.O + o] = v;
    }
  }
  if constexpr (EMODE == 1) {
    float* red0 = smem;
    float* red1 = smem + 1024;
#pragma unroll
    for (int j = 0; j < 4; ++j) {
      float s0 = 0.f, s1 = 0.f;
#pragma unroll
      for (int i = 0; i < 4; ++i) { float v = acc[i][j]; s0 += v; s1 += v * v; }
      red0[tr * 64 + tc * 4 + j] = s0;
      red1[tr * 64 + tc * 4 + j] = s1;
    }
    __syncthreads();
    for (int st = 8; st >= 1; st >>= 1) {
      if (tr < st) {
#pragma unroll
        for (int j = 0; j < 4; ++j) {
          int cix = tc * 4 + j;
          red0[tr * 64 + cix] += red0[(tr + st) * 64 + cix];
          red1[tr * 64 + cix] += red1[(tr + st) * 64 + cix];
        }
      }
      __syncthreads();
    }
    if (tr == 0) {
      size_t base = ((size_t)rt * g.numOt + ot) * 128;
#pragma unroll
      for (int j = 0; j < 4; ++j) {
        int cix = tc * 4 + j;
        g.partial[base + cix] = red0[cix];
        g.partial[base + 64 + cix] = red1[cix];
      }
    }
  }
}

// ================= stats / bn =================
__global__ void reduce_finalize_kernel(const float* partial, float2* stats2,
                                       int Rt, int numOt, int R, int O) {
  int o = blockIdx.x;
  int ot = o >> 6, oo = o & 63;
  int tid = threadIdx.x;
  double s = 0.0, s2 = 0.0;
  for (int rtt = tid; rtt < Rt; rtt += 256) {
    const float* p = partial + ((size_t)rtt * numOt + ot) * 128;
    s += (double)p[oo];
    s2 += (double)p[64 + oo];
  }
  __shared__ double r0[256], r1[256];
  r0[tid] = s; r1[tid] = s2;
  __syncthreads();
  for (int st = 128; st > 0; st >>= 1) {
    if (tid < st) { r0[tid] += r0[tid + st]; r1[tid] += r1[tid + st]; }
    __syncthreads();
  }
  if (tid == 0) {
    double mu = r0[0] / R;
    double var = r1[0] / R - mu * mu;
    stats2[o] = make_float2((float)mu, 1.f / sqrtf((float)var + EPSV));
  }
}

template <bool BF16>
__global__ void bn_apply_relu_kernel(void* xv, const float2* stats2, long long tot, int C) {
  float* xf = (float*)xv;
  __hip_bfloat16* xb = (__hip_bfloat16*)xv;
  for (long long gidx = (long long)blockIdx.x * blockDim.x + threadIdx.x; gidx < tot;
       gidx += (long long)gridDim.x * blockDim.x) {
    int c = (int)(gidx % C);
    float2 st = stats2[c];
    float v = BF16 ? __bfloat162float(xb[gidx]) : xf[gidx];
    float y = fmaxf((v - st.x) * st.y, 0.f);
    if (BF16) xb[gidx] = __float2bfloat16(y);
    else xf[gidx] = y;
  }
}

// ================= misc =================
__global__ void mean_xyz_kernel(const float* xyz, float* bmean, int N) {
  int b = blockIdx.x, tid = threadIdx.x;
  __shared__ float s[3][256];
  float sx = 0, sy = 0, sz = 0;
  for (int n = tid; n < N; n += 256) {
    const float* p = xyz + ((size_t)b * N + n) * 3;
    sx += p[0]; sy += p[1]; sz += p[2];
  }
  s[0][tid] = sx; s[1][tid] = sy; s[2][tid] = sz;
  __syncthreads();
  for (int st = 128; st > 0; st >>= 1) {
    if (tid < st) {
      s[0][tid] += s[0][tid + st];
      s[1][tid] += s[1][tid + st];
      s[2][tid] += s[2][tid + st];
    }
    __syncthreads();
  }
  if (tid < 3) bmean[b * 3 + tid] = s[tid][0] / (float)N;
}

__global__ void centers_kernel(const float* xyz, float* ctr, int B, int N, int M) {
  int g = blockIdx.x * blockDim.x + threadIdx.x;
  if (g >= B * M) return;
  int b = g / M, m = g % M;
  float delta = (float)(N - 1) / (float)(M - 1);
  int n = (int)((float)m * delta);
  if (n > N - 1) n = N - 1;
  ctr[(size_t)g * 3 + 0] = xyz[((size_t)b * N + n) * 3 + 0];
  ctr[(size_t)g * 3 + 1] = xyz[((size_t)b * N + n) * 3 + 1];
  ctr[(size_t)g * 3 + 2] = xyz[((size_t)b * N + n) * 3 + 2];
}

// KNN with per-lane sorted top-4 head lists (verified R15; 16-wave blocks verified R22)
__global__ __launch_bounds__(1024) void knn_heads_kernel(const float* xyz, const float* ctr,
                                                         int* idx_out, int B, int N, int M) {
  extern __shared__ float sm[];
  const int pitch = N + (N >> 6);
  float* xs = sm;
  float* ys = sm + pitch;
  float* zs = sm + 2 * pitch;
  const int b = blockIdx.y;
  const int tid = threadIdx.x;
  const float* xb = xyz + (size_t)b * N * 3;
  for (int i = tid; i < N; i += blockDim.x) {
    int pi = i + (i >> 6);
    xs[pi] = xb[i * 3 + 0];
    ys[pi] = xb[i * 3 + 1];
    zs[pi] = xb[i * 3 + 2];
  }
  __syncthreads();
  const int w = tid >> 6, lane = tid & 63;
  const int wpb = blockDim.x >> 6;
  const int m = blockIdx.x * wpb + w;
  if (m >= M) return;
  const int bm = b * M + m;
  const float cx = ctr[(size_t)bm * 3], cy = ctr[(size_t)bm * 3 + 1], cz = ctr[(size_t)bm * 3 + 2];
  const float cc = cx * cx + cy * cy + cz * cz;
  const int npl = N >> 6;
  const int shift = 31 - __clz(npl);
  const int base = lane * npl;
  const int pb = base + (base >> 6);
  const float INF = 3.4e38f;
  const int IMAX = 0x7fffffff;

  float a0 = INF, a1 = INF, a2 = INF, a3 = INF;
  int i0 = IMAX, i1 = IMAX, i2 = IMAX, i3 = IMAX;
  for (int j = 0; j < npl; ++j) {
    float x = xs[pb + j], y = ys[pb + j], z = zs[pb + j];
    float d2 = cc + (x * x + y * y + z * z) - 2.f * (cx * x + cy * y + cz * z);
    int gj = base + j;
    bool lt0 = (d2 < a0) || (d2 == a0 && gj < i0);
    bool lt1 = (d2 < a1) || (d2 == a1 && gj < i1);
    bool lt2 = (d2 < a2) || (d2 == a2 && gj < i2);
    bool lt3 = (d2 < a3) || (d2 == a3 && gj < i3);
    float na3 = lt2 ? a2 : (lt3 ? d2 : a3); int ni3 = lt2 ? i2 : (lt3 ? gj : i3);
    float na2 = lt1 ? a1 : (lt2 ? d2 : a2); int ni2 = lt1 ? i1 : (lt2 ? gj : i2);
    float na1 = lt0 ? a0 : (lt1 ? d2 : a1); int ni1 = lt0 ? i0 : (lt1 ? gj : i1);
    float na0 = lt0 ? d2 : a0;              int ni0 = lt0 ? gj : i0;
    a0 = na0; a1 = na1; a2 = na2; a3 = na3;
    i0 = ni0; i1 = ni1; i2 = ni2; i3 = ni3;
  }

  unsigned int rmlo = 0u, rmhi = 0u;
  int remaining = npl;

  for (int sel = 0; sel < KN; ++sel) {
    float d = a0;
    int ii = i0;
#pragma unroll
    for (int off = 1; off < 64; off <<= 1) {
      float od = __shfl_xor(d, off);
      int oi = __shfl_xor(ii, off);
      if (od < d || (od == d && oi < ii)) { d = od; ii = oi; }
    }
    if (lane == 0) idx_out[(size_t)bm * KN + sel] = ii;
    const int owner = ii >> shift;
    if (lane == owner) {
      int jin = ii - (owner << shift);
      if (jin < 32) rmlo |= 1u << jin;
      else rmhi |= 1u << (jin - 32);
      remaining--;
      a0 = a1; i0 = i1; a1 = a2; i1 = i2; a2 = a3; i2 = i3;
      a3 = INF; i3 = IMAX;
    }
    if (sel == KN - 1) break;
    float h = __shfl(a0, owner);
    int remo = __shfl(remaining, owner);
    if (h >= INF && remo > 0) {
      unsigned int olo = __shfl(rmlo, owner);
      unsigned int ohi = __shfl(rmhi, owner);
      const int obase = owner << shift;
      const int opb = obase + (obase >> 6);
      float c0 = INF, c1 = INF, c2 = INF, c3 = INF;
      int jc0 = IMAX, jc1 = IMAX, jc2 = IMAX, jc3 = IMAX;
      if (lane < npl) {
        bool rem = (lane < 32) ? ((olo >> lane) & 1u) : ((ohi >> (lane - 32)) & 1u);
        if (!rem) {
          float x = xs[opb + lane], y = ys[opb + lane], z = zs[opb + lane];
          c0 = cc + (x * x + y * y + z * z) - 2.f * (cx * x + cy * y + cz * z);
          jc0 = obase + lane;
        }
      }
#pragma unroll
      for (int off = 1; off < 64; off <<= 1) {
        float b0v = __shfl_xor(c0, off), b1v = __shfl_xor(c1, off);
        float b2v = __shfl_xor(c2, off), b3v = __shfl_xor(c3, off);
        int d0v = __shfl_xor(jc0, off), d1v = __shfl_xor(jc1, off);
        int d2v = __shfl_xor(jc2, off), d3v = __shfl_xor(jc3, off);
        bool t1 = (c0 < b0v) || (c0 == b0v && jc0 < d0v);
        float o0 = t1 ? c0 : b0v; int p0 = t1 ? jc0 : d0v;
        float A0 = t1 ? c1 : c0, A1 = t1 ? c2 : c1, A2 = t1 ? c3 : c2;
        int IA0 = t1 ? jc1 : jc0, IA1 = t1 ? jc2 : jc1, IA2 = t1 ? jc3 : jc2;
        float B0 = t1 ? b0v : b1v, B1 = t1 ? b1v : b2v, B2 = t1 ? b2v : b3v;
        int IB0 = t1 ? d0v : d1v, IB1 = t1 ? d1v : d2v, IB2 = t1 ? d2v : d3v;
        bool t2 = (A0 < B0) || (A0 == B0 && IA0 < IB0);
        float o1 = t2 ? A0 : B0; int p1 = t2 ? IA0 : IB0;
        float A0b = t2 ? A1 : A0, A1b = t2 ? A2 : A1;
        int IA0b = t2 ? IA1 : IA0, IA1b = t2 ? IA2 : IA1;
        float B0b = t2 ? B0 : B1, B1b = t2 ? B1 : B2;
        int IB0b = t2 ? IB0 : IB1, IB1b = t2 ? IB1 : IB2;
        bool t3 = (A0b < B0b) || (A0b == B0b && IA0b < IB0b);
        float o2 = t3 ? A0b : B0b; int p2 = t3 ? IA0b : IB0b;
        float A0c = t3 ? A1b : A0b; int IA0c = t3 ? IA1b : IA0b;
        float B0c = t3 ? B0b : B1b; int IB0c = t3 ? IB0b : IB1b;
        bool t4 = (A0c < B0c) || (A0c == B0c && IA0c < IB0c);
        float o3 = t4 ? A0c : B0c; int p3 = t4 ? IA0c : IB0c;
        c0 = o0; c1 = o1; c2 = o2; c3 = o3;
        jc0 = p0; jc1 = p1; jc2 = p2; jc3 = p3;
      }
      if (lane == owner) {
        a0 = c0; a1 = c1; a2 = c2; a3 = c3;
        i0 = jc0; i1 = jc1; i2 = jc2; i3 = jc3;
      }
    }
  }
}

// interp3, 4 scanners per low-res point (verified R14)
__global__ __launch_bounds__(256) void interp3_par_kernel(const float* xl, const float* xh,
                                                          int* idx3, float* w3, int Nl, int Nh) {
  extern __shared__ float sm[];
  float* xs = sm;
  float* ys = sm + Nh;
  float* zs = sm + 2 * Nh;
  const int b = blockIdx.y;
  const int tid = threadIdx.x;
  const float* xb = xh + (size_t)b * Nh * 3;
  for (int i = tid; i < Nh; i += 256) {
    xs[i] = xb[i * 3 + 0];
    ys[i] = xb[i * 3 + 1];
    zs[i] = xb[i * 3 + 2];
  }
  __syncthreads();
  const int pt = tid >> 2, sc = tid & 3;
  const int l = blockIdx.x * 64 + pt;
  if (l >= Nl) return;
  const size_t g = (size_t)b * Nl + l;
  const float px = xl[g * 3], py = xl[g * 3 + 1], pz = xl[g * 3 + 2];
  const float pp = px * px + py * py + pz * pz;
  const int chunk = Nh >> 2;
  const int j0 = sc * chunk, j1 = j0 + chunk;
  float a0 = 3.4e38f, a1 = 3.4e38f, a2 = 3.4e38f;
  int i0 = 0x7fffffff, i1 = 0x7fffffff, i2 = 0x7fffffff;
  for (int j = j0; j < j1; ++j) {
    float x = xs[j], y = ys[j], z = zs[j];
    float d2 = (pp + (x * x + y * y + z * z)) - 2.f * (px * x + py * y + pz * z);
    if (d2 < a0) {
      a2 = a1; i2 = i1; a1 = a0; i1 = i0; a0 = d2; i0 = j;
    } else if (d2 < a1) {
      a2 = a1; i2 = i1; a1 = d2; i1 = j;
    } else if (d2 < a2) {
      a2 = d2; i2 = j;
    }
  }
#pragma unroll
  for (int off = 1; off < 4; off <<= 1) {
    float b0 = __shfl_xor(a0, off), b1 = __shfl_xor(a1, off), b2 = __shfl_xor(a2, off);
    int c0 = __shfl_xor(i0, off), c1 = __shfl_xor(i1, off), c2 = __shfl_xor(i2, off);
    bool t = (a0 < b0) || (a0 == b0 && i0 < c0);
    float o0 = t ? a0 : b0; int oi0 = t ? i0 : c0;
    float na0 = t ? a1 : a0, na1 = t ? a2 : a1;
    int nia0 = t ? i1 : i0, nia1 = t ? i2 : i1;
    float nb0 = t ? b0 : b1, nb1 = t ? b1 : b2;
    int nib0 = t ? c0 : c1, nib1 = t ? c1 : c2;
    bool t2 = (na0 < nb0) || (na0 == nb0 && nia0 < nib0);
    float o1 = t2 ? na0 : nb0; int oi1 = t2 ? nia0 : nib0;
    float ma0 = t2 ? na1 : na0; int mia0 = t2 ? nia1 : nia0;
    float mb0 = t2 ? nb0 : nb1; int mib0 = t2 ? nib0 : nib1;
    bool t3 = (ma0 < mb0) || (ma0 == mb0 && mia0 < mib0);
    float o2 = t3 ? ma0 : mb0; int oi2 = t3 ? mia0 : mib0;
    a0 = o0; a1 = o1; a2 = o2; i0 = oi0; i1 = oi1; i2 = oi2;
  }
  if (sc == 0) {
    float d0 = fmaxf(sqrtf(fmaxf(a0, 0.f)), 1e-8f);
    float d1 = fmaxf(sqrtf(fmaxf(a1, 0.f)), 1e-8f);
    float d2_ = fmaxf(sqrtf(fmaxf(a2, 0.f)), 1e-8f);
    float w0 = 1.f / d0, w1 = 1.f / d1, w2 = 1.f / d2_;
    float s = w0 + w1 + w2;
    idx3[g * 3 + 0] = i0;
    idx3[g * 3 + 1] = i1;
    idx3[g * 3 + 2] = i2;
    w3[g * 3 + 0] = w0 / s;
    w3[g * 3 + 1] = w1 / s;
    w3[g * 3 + 2] = w2 / s;
  }
}

__global__ void buildx_kernel(const float* fh, const float* fl, const int* idx3, const float* w3,
                              float* xout, int B, int Nl, int Nh, int Ch, int Cl) {
  int Cx = Ch + Cl;
  size_t tot = (size_t)B * Nl * Cx;
  for (size_t g = (size_t)blockIdx.x * blockDim.x + threadIdx.x; g < tot;
       g += (size_t)gridDim.x * blockDim.x) {
    int r = (int)(g / Cx), c = (int)(g % Cx);
    int b = r / Nl;
    if (c < Ch) {
      float s = 0.f;
      for (int j = 0; j < 3; ++j) {
        int n = idx3[(size_t)r * 3 + j];
        s += w3[(size_t)r * 3 + j] * fh[((size_t)b * Nh + n) * Ch + c];
      }
      xout[g] = s;
    } else {
      xout[g] = fl[(size_t)r * Cl + (c - Ch)];
    }
  }
}

// ================= host =================
extern "C" void kernel_launch(void* const* d_in, const int* in_sizes, int n_in,
                              void* d_out, int out_size, void* d_ws, size_t ws_size,
                              hipStream_t stream) {
  const int B = 8, N = 4096;
  const float* X = (const float*)d_in[0];
  const float* W_spfe1 = (const float*)d_in[1];
  const float* W_spfe2 = (const float*)d_in[3];
  const float* Wf1 = (const float*)d_in[5];
  const float* Wa1 = (const float*)d_in[7];
  const float* Wf2 = (const float*)d_in[9];
  const float* Wa2 = (const float*)d_in[11];
  const float* Wf3 = (const float*)d_in[13];
  const float* Wa3 = (const float*)d_in[15];
  const float* Wfp3 = (const float*)d_in[17];
  const float* Wfp2 = (const float*)d_in[19];
  const float* Wfp1 = (const float*)d_in[21];
  const float* Wh1 = (const float*)d_in[23];
  const float* Wh2 = (const float*)d_in[25];
  const float* bh2 = (const float*)d_in[26];
  float* out = (float*)d_out;

  char* wp = (char*)d_ws;
  auto alloc = [&](size_t bytes) -> void* {
    void* p = (void*)wp;
    wp += (bytes + 255) & ~(size_t)255;
    return p;
  };
  float2* stats2 = (float2*)alloc(512 * sizeof(float2) * 2);
  float* partial = (float*)alloc((size_t)8192 * 128 * 4);
  float* bmean = (float*)alloc(B * 3 * sizeof(float));
  float* f0 = (float*)alloc((size_t)B * N * 64 * 4);
  float* xyz1 = (float*)alloc((size_t)B * 1024 * 3 * 4);
  float* xyz2 = (float*)alloc((size_t)B * 512 * 3 * 4);
  float* xyz3 = (float*)alloc((size_t)B * 256 * 3 * 4);
  float* f1 = (float*)alloc((size_t)B * 1024 * 128 * 4);
  float* f2 = (float*)alloc((size_t)B * 512 * 256 * 4);
  float* f3 = (float*)alloc((size_t)B * 256 * 512 * 4);
  float* fpmean = (float*)alloc((size_t)B * 1024 * 128 * 4);
  __hip_bfloat16* fpmeanb = (__hip_bfloat16*)alloc((size_t)B * 1024 * 128 * 2);
  int* idxb = (int*)alloc((size_t)B * 1024 * KN * 4);
  int* idx3 = (int*)alloc((size_t)B * 4096 * 3 * 4);
  float* w3 = (float*)alloc((size_t)B * 4096 * 3 * 4);
  void* BIG = alloc((size_t)33554432 * 2);  // 64 MB: fp bf16 / f32 scratch
  size_t fup_off = (size_t)(wp - (char*)d_ws);
  float* fup2 = (float*)alloc((size_t)B * 512 * 256 * 4);
  float* fup1 = (float*)alloc((size_t)B * 1024 * 128 * 4);
  float* fup0 = (float*)alloc((size_t)B * 4096 * 128 * 4);
  // alpha aliases the fup region (disjoint lifetimes), 64 MB
  __hip_bfloat16* alphaBuf_all = (__hip_bfloat16*)((char*)d_ws + fup_off);
  size_t alpha_end = fup_off + (size_t)67108864;
  char* wp2 = (char*)d_ws + alpha_end;
  if (wp2 < wp) wp2 = wp;
  __hip_bfloat16* Gfb = (__hip_bfloat16*)wp2; wp2 += (size_t)8 * 1024 * 1024;
  __hip_bfloat16* Gab = (__hip_bfloat16*)wp2; wp2 += (size_t)8 * 1024 * 1024;
  float* Gm = (float*)wp2; wp2 += (size_t)4 * 1024 * 1024;
  __hip_bfloat16* Wbuf = (__hip_bfloat16*)wp2; wp2 += (size_t)2 * 1024 * 1024;  // bf16 W repack

  auto run_stats = [&](int R, int O) {
    reduce_finalize_kernel<<<O, 256, 0, stream>>>(partial, stats2, R / 64, O / 64, R, O);
  };
  auto run_bn = [&](void* x, int R, int C, bool bf) {
    long long tot = (long long)R * C;
    int blocks = (int)((tot + 255) / 256);
    if (blocks > 4096) blocks = 4096;
    if (bf) bn_apply_relu_kernel<true><<<blocks, 256, 0, stream>>>(x, stats2, tot, C);
    else bn_apply_relu_kernel<false><<<blocks, 256, 0, stream>>>(x, stats2, tot, C);
  };
  auto run_knn = [&](const float* xyz_in, const float* ctr, int Nc, int M) {
    int pitch = Nc + (Nc >> 6);
    size_t sm = (size_t)3 * pitch * 4;
    int wpb = ((M % 16) == 0) ? 16 : 4;
    knn_heads_kernel<<<dim3(M / wpb, B), wpb * 64, sm, stream>>>(xyz_in, ctr, idxb, B, Nc, M);
  };
  auto run_convw = [&](const float* W, int wk, int colOff, int O, int K, __hip_bfloat16* dst) {
    long long tot = (long long)O * K;
    convw_kernel<<<(int)((tot + 255) / 256), 256, 0, stream>>>(W, dst, wk, colOff, tot, K);
  };

  // ---- SPFE (fp32, small K) ----
  mean_xyz_kernel<<<B, 256, 0, stream>>>(X, bmean, N);
  float* hbuf = (float*)BIG;
  {
    GemmArgs g{};
    g.W = W_spfe1; g.out = hbuf; g.partial = partial;
    g.R = B * N; g.K = 9; g.O = 64; g.numOt = 1;
    g.xyz = X; g.bmean = bmean; g.Ncur = N;
    gemm_dense<1, 3><<<dim3(g.R / 64, 1), 256, 0, stream>>>(g);
    run_stats(g.R, g.O); run_bn(hbuf, g.R, g.O, false);
  }
  {
    GemmArgs g{};
    g.A = hbuf; g.W = W_spfe2; g.out = f0; g.partial = partial;
    g.R = B * N; g.K = 64; g.O = 64; g.numOt = 1;
    gemm_dense<1, 0><<<dim3(g.R / 64, 1), 256, 0, stream>>>(g);
    run_stats(g.R, g.O); run_bn(f0, g.R, g.O, false);
  }

  // ---- SA path (dense decomposed, pipelined GEMM, bf16-W, fused bn+fpmean) ----
  auto sa = [&](const float* xyz_in, const float* feat_in, int Nc, int M, int Cf, int Of,
                const float* Wf, const float* Wa, float* xyz_out, float* f_out) {
    int BM = B * M, R = BM * KN, NR = B * Nc;
    int wkF = 3 + Cf, wkA = 3 + Cf + Of;
    centers_kernel<<<ceil_div(BM, 256), 256, 0, stream>>>(xyz_in, xyz_out, B, Nc, M);
    run_knn(xyz_in, xyz_out, Nc, M);
    __hip_bfloat16* fpbuf = (__hip_bfloat16*)BIG;
    {  // [Gf | Ga] = feat . [Wf[:,3:3+Cf] ; Wa[:,3:3+Cf]]  (fused: one A pass)
      run_convw(Wf, wkF, 3, Of, Cf, Wbuf);
      run_convw(Wa, wkA, 3, Of, Cf, Wbuf + (size_t)Of * Cf);
      MdArgs m{}; m.Af = feat_in; m.lda = Cf;
      m.Wb = (const unsigned short*)Wbuf;
      m.R = NR; m.K = Cf; m.O = 2 * Of; m.Oh = Of;
      m.outb = Gfb; m.outb2 = Gab; m.numOt = (2 * Of) / 64;
      gemm_mdw<1, false, true><<<dim3(((2 * Of) / 64) * (NR / 128)), 256, 0, stream>>>(m);
    }
    combine_fp_kernel<<<dim3(R / 64, Of / 64), 256, 0, stream>>>(
        (const unsigned short*)Gfb, Wf, wkF, xyz_in, xyz_out, idxb, fpbuf,
        partial, Of / 64, M, Nc, Of);
    run_stats(R, Of);
    bn_fpmean_kernel<<<dim3(BM / 4, Of / 64), 256, 0, stream>>>(fpbuf, stats2, fpmeanb, Of);
    // WaP repack shared by Gm and alpha
    run_convw(Wa, wkA, 3 + Cf, Of, Of, Wbuf);
    {  // Gm = fpmean . Wa[:,3+Cf:]
      MdArgs m{}; m.Ab = (const unsigned short*)fpmeanb; m.lda = Of; m.W = Wa; m.wk = wkA;
      m.colOff = 3 + Cf; m.Wb = (const unsigned short*)Wbuf;
      m.R = BM; m.K = Of; m.O = Of; m.outf = Gm; m.numOt = Of / 64;
      gemm_mdw<0, true, true><<<dim3((Of / 64) * (BM / 128)), 256, 0, stream>>>(m);
    }
    {  // alpha = fp . Wa_p + Ga[nbr] + nx.Wa_x - Gm[bm]  (+ partials)
      MdArgs m{}; m.Ab = (const unsigned short*)fpbuf; m.lda = Of; m.W = Wa; m.wk = wkA;
      m.colOff = 3 + Cf; m.Wb = (const unsigned short*)Wbuf;
      m.R = R; m.K = Of; m.O = Of;
      m.outb = alphaBuf_all; m.partial = partial; m.numOt = Of / 64;
      m.Ga = (const unsigned short*)Gab; m.Gm = Gm;
      m.xyz = xyz_in; m.ctr = xyz_out; m.idx = idxb; m.M = M; m.Ncur = Nc;
      gemm_mdw<2, true, true><<<dim3((Of / 64) * (R / 128)), 256, 0, stream>>>(m);
    }
    run_stats(R, Of);
    apply_lite_kernel<<<dim3(BM / 4, Of / 64), 256, 0, stream>>>(alphaBuf_all, fpbuf, stats2, f_out, Of);
  };

  sa(X, f0, 4096, 1024, 64, 128, Wf1, Wa1, xyz1, f1);
  sa(xyz1, f1, 1024, 512, 128, 256, Wf2, Wa2, xyz2, f2);
  sa(xyz2, f2, 512, 256, 256, 512, Wf3, Wa3, xyz3, f3);

  // ---- FP layers (bf16 MFMA wide, EP3, bf16-W) ----
  auto fpl = [&](const float* xl, const float* xh, const float* fl, const float* fh,
                 int Nl, int Nh, int Cl, int Ch, const float* W, float* f_up, int O) {
    size_t smI = (size_t)3 * Nh * 4;
    interp3_par_kernel<<<dim3(ceil_div(Nl, 64), B), 256, smI, stream>>>(xl, xh, idx3, w3, Nl, Nh);
    float* xbuf = (float*)BIG;
    int Cx = Ch + Cl;
    size_t tot = (size_t)B * Nl * Cx;
    int blocks = (int)((tot + 255) / 256);
    if (blocks > 4096) blocks = 4096;
    buildx_kernel<<<blocks, 256, 0, stream>>>(fh, fl, idx3, w3, xbuf, B, Nl, Nh, Ch, Cl);
    run_convw(W, Cx, 0, O, Cx, Wbuf);
    MdArgs m{};
    m.Af = xbuf; m.lda = Cx; m.W = W; m.wk = Cx; m.colOff = 0;
    m.R = B * Nl; m.K = Cx; m.O = O;
    m.Wb = (const unsigned short*)Wbuf;
    m.outf = f_up; m.partial = partial; m.numOt = O / 64;
    gemm_mdw<3, false, true><<<dim3((O / 64) * (m.R / 128)), 256, 0, stream>>>(m);
    run_stats(m.R, O); run_bn(f_up, m.R, O, false);
  };

  fpl(xyz2, xyz3, f2, f3, 512, 256, 256, 512, Wfp3, fup2, 256);
  fpl(xyz1, xyz2, f1, fup2, 1024, 512, 128, 256, Wfp2, fup1, 128);
  fpl(X, xyz1, f0, fup1, 4096, 1024, 64, 128, Wfp1, fup0, 128);

  // ---- head ----
  float* hh = (float*)BIG;
  {
    run_convw(Wh1, 128, 0, 128, 128, Wbuf);
    MdArgs m{};
    m.Af = fup0; m.lda = 128; m.W = Wh1; m.wk = 128; m.colOff = 0;
    m.Wb = (const unsigned short*)Wbuf;
    m.R = B * N; m.K = 128; m.O = 128;
    m.outf = hh; m.partial = partial; m.numOt = 2;
    gemm_mdw<3, false, true><<<dim3(2 * (m.R / 128)), 256, 0, stream>>>(m);
    run_stats(m.R, m.O); run_bn(hh, m.R, m.O, false);
  }
  {
    GemmArgs g{};
    g.A = hh; g.W = Wh2; g.bias = bh2; g.out = out;
    g.R = B * N; g.K = 128; g.O = 50; g.numOt = 1;
    gemm_dense<0, 0><<<dim3(g.R / 64, 1), 256, 0, stream>>>(g);
  }
}

// Round 28
// 934.233 us; speedup vs baseline: 1.0142x; 1.0142x over previous
//
#include <hip/hip_runtime.h>
#include <hip/hip_bf16.h>
#include <cstdint>
#include <cstddef>

#define KN 32
#define EPSV 1e-5f
#define BR 64
#define BO 64
#define BKK 16
#define ASTR 68   // fp32 LDS tile stride (dense fp32 kernel)
#define BKM 32    // mfma K-chunk
#define BKP 40    // bf16 LDS row stride in shorts (80B: 16B-aligned, bank-spread)

typedef float f32x4 __attribute__((ext_vector_type(4)));
typedef __bf16 bf16x8 __attribute__((ext_vector_type(8)));
typedef unsigned short ushort8 __attribute__((ext_vector_type(8)));

static inline int ceil_div(int a, int b) { return (a + b - 1) / b; }

__device__ __forceinline__ float b2f(unsigned short u) {
  union { float f; uint32_t i; } x;
  x.i = (uint32_t)u << 16;
  return x.f;
}

__device__ __forceinline__ unsigned short f2bu(float f) {
  __hip_bfloat16 h = __float2bfloat16(f);
  union { __hip_bfloat16 h; unsigned short u; } c;
  c.h = h;
  return c.u;
}

// ================= fp32 -> bf16 row-major W repack =================
__global__ void convw_kernel(const float* W, __hip_bfloat16* Wb, int wk, int colOff,
                             long long tot, int K) {
  long long i = (long long)blockIdx.x * blockDim.x + threadIdx.x;
  if (i >= tot) return;
  int o = (int)(i / K), c = (int)(i % K);
  Wb[i] = __float2bfloat16(W[(size_t)o * wk + colOff + c]);
}

// ================= wide (128-row) dense bf16-MFMA GEMM =================
// R17 tile + R21 XCD swizzle + R23 pipelined staging + R26 Ga/Gm reg prefetch.
// R28: TWO 32-K chunks per barrier pair ([A0|W0|A1|W1] LDS): halves the
// __syncthreads count per K and deepens the load pipeline (6 loads in flight).
// MFMA order (chunk a fully, then chunk b) identical to the sequential loop
// -> bit-identical accumulation. Requires K % 64 == 0 (true at every site).
struct MdArgs {
  const float* Af; const unsigned short* Ab; int lda;
  const float* W; int wk; int colOff;
  const unsigned short* Wb;   // dense bf16 [O][K] repack (WBF16 path)
  float* outf; __hip_bfloat16* outb;
  __hip_bfloat16* outb2; int Oh;   // EP1 split store (fused Gf|Ga)
  float* partial; int numOt;
  const unsigned short* Ga; const float* Gm;
  const float* xyz; const float* ctr; const int* idx;
  int M, Ncur;
  int R, K, O;
};

template <int EP, bool ABF16, bool WBF16>
__global__ __launch_bounds__(256) void gemm_mdw(MdArgs g) {
  constexpr int SMEMB = 384 * BKP * 2;   // [A0|W0|A1|W1] = 30720 B; EP2 reuse (20480) fits
  __shared__ __align__(16) char smemraw[SMEMB];
  __shared__ float nxs[128][3];
  __shared__ float waxs[64][3];
  __shared__ int grow[128];
  __hip_bfloat16* As = (__hip_bfloat16*)smemraw;        // chunk a: A[128][BKP]
  __hip_bfloat16* Ws = As + 128 * BKP;                  // chunk a: W[64][BKP]
  __hip_bfloat16* As2 = As + 192 * BKP;                 // chunk b: A[128][BKP]
  __hip_bfloat16* Ws2 = As + 320 * BKP;                 // chunk b: W[64][BKP]
  const int tid = threadIdx.x;
  const int lane = tid & 63, w = tid >> 6;
  // XCD-aware decode: per-XCD contiguous rt-slab, ot fastest within the slab.
  const int cpx = gridDim.x >> 3;
  const int s = (blockIdx.x & 7) * cpx + (blockIdx.x >> 3);
  const int rt = s / g.numOt;
  const int ot = s - rt * g.numOt;
  const int br0 = rt * 128, bo0 = ot * BO;

  ushort8 rGa[4];
  float gmv;
  if constexpr (EP == 2) {
    if (tid < 128) {
      int r = br0 + tid;
      int bm = r >> 5;
      int b = bm / g.M;
      int n = g.idx[(size_t)bm * KN + (r & (KN - 1))];
      int nb = b * g.Ncur + n;
      grow[tid] = nb;
      nxs[tid][0] = g.xyz[(size_t)nb * 3 + 0] - g.ctr[(size_t)bm * 3 + 0];
      nxs[tid][1] = g.xyz[(size_t)nb * 3 + 1] - g.ctr[(size_t)bm * 3 + 1];
      nxs[tid][2] = g.xyz[(size_t)nb * 3 + 2] - g.ctr[(size_t)bm * 3 + 2];
    } else if (tid < 192) {
      int o = tid - 128;
      waxs[o][0] = g.W[(size_t)(bo0 + o) * g.wk + 0];
      waxs[o][1] = g.W[(size_t)(bo0 + o) * g.wk + 1];
      waxs[o][2] = g.W[(size_t)(bo0 + o) * g.wk + 2];
    }
    __syncthreads();
    // prefetch gathered Ga tile + Gm row into regs; latency hides under K-loop
#pragma unroll
    for (int p = 0; p < 4; ++p) {
      int i = tid + p * 256;
      int rl = i >> 3, sg = (i & 7) * 8;
      rGa[p] = *(const ushort8*)(g.Ga + (size_t)grow[rl] * g.O + bo0 + sg);
    }
    gmv = g.Gm[(size_t)((br0 >> 5) + (tid >> 6)) * g.O + bo0 + (tid & 63)];
  }

  f32x4 acc[2][4] = {};
  const int arow0 = (w * 16 + (lane & 15)) * BKP + (lane >> 4) * 8;
  const int arow1 = arow0 + 64 * BKP;
  const int sr = tid >> 2;          // staging row (0..63; +64 for 2nd half)
  const int sc8 = (tid & 3) * 8;    // staging k-offset
  const int wr = tid >> 2;
  const int wkb = (tid & 3) * 8;
  const float* wrow = WBF16 ? nullptr : (g.W + (size_t)(bo0 + wr) * g.wk + g.colOff);

  auto loadChunk = [&](int kk, ushort8& a0, ushort8& a1, ushort8& ww) {
    if constexpr (ABF16) {
      a0 = *(const ushort8*)(g.Ab + (size_t)(br0 + sr) * g.lda + kk + sc8);
      a1 = *(const ushort8*)(g.Ab + (size_t)(br0 + 64 + sr) * g.lda + kk + sc8);
    } else {
      const float* ap0 = g.Af + (size_t)(br0 + sr) * g.lda + kk + sc8;
      const float* ap1 = g.Af + (size_t)(br0 + 64 + sr) * g.lda + kk + sc8;
#pragma unroll
      for (int e = 0; e < 8; ++e) { a0[e] = f2bu(ap0[e]); a1[e] = f2bu(ap1[e]); }
    }
    if constexpr (WBF16) {
      ww = *(const ushort8*)(g.Wb + (size_t)(bo0 + wr) * g.K + kk + wkb);
    } else {
#pragma unroll
      for (int e = 0; e < 8; ++e) ww[e] = f2bu(wrow[kk + wkb + e]);
    }
  };

  // ---- prologue: load chunk pair (k=0, k=BKM) into registers ----
  ushort8 rA0, rA1, rW, rB0, rB1, rWb;
  loadChunk(0, rA0, rA1, rW);
  loadChunk(BKM, rB0, rB1, rWb);

  for (int k0 = 0; k0 < g.K; k0 += 2 * BKM) {
    // ---- write both chunks to LDS ----
    *(ushort8*)((unsigned short*)As + sr * BKP + sc8) = rA0;
    *(ushort8*)((unsigned short*)As + (64 + sr) * BKP + sc8) = rA1;
    *(ushort8*)((unsigned short*)Ws + wr * BKP + wkb) = rW;
    *(ushort8*)((unsigned short*)As2 + sr * BKP + sc8) = rB0;
    *(ushort8*)((unsigned short*)As2 + (64 + sr) * BKP + sc8) = rB1;
    *(ushort8*)((unsigned short*)Ws2 + wr * BKP + wkb) = rWb;
    __syncthreads();
    // ---- issue next pair's loads (latency hidden under compute) ----
    ushort8 nA0, nA1, nW, nB0, nB1, nWb;
    const int k1 = k0 + 2 * BKM;
    if (k1 < g.K) {
      loadChunk(k1, nA0, nA1, nW);
      loadChunk(k1 + BKM, nB0, nB1, nWb);
    }
    // ---- compute: chunk a then chunk b (same order as sequential loop) ----
    {
      bf16x8 av0 = *(const bf16x8*)(As + arow0);
      bf16x8 av1 = *(const bf16x8*)(As + arow1);
#pragma unroll
      for (int nf = 0; nf < 4; ++nf) {
        bf16x8 bv = *(const bf16x8*)(Ws + (nf * 16 + (lane & 15)) * BKP + (lane >> 4) * 8);
        acc[0][nf] = __builtin_amdgcn_mfma_f32_16x16x32_bf16(av0, bv, acc[0][nf], 0, 0, 0);
        acc[1][nf] = __builtin_amdgcn_mfma_f32_16x16x32_bf16(av1, bv, acc[1][nf], 0, 0, 0);
      }
    }
    {
      bf16x8 av0 = *(const bf16x8*)(As2 + arow0);
      bf16x8 av1 = *(const bf16x8*)(As2 + arow1);
#pragma unroll
      for (int nf = 0; nf < 4; ++nf) {
        bf16x8 bv = *(const bf16x8*)(Ws2 + (nf * 16 + (lane & 15)) * BKP + (lane >> 4) * 8);
        acc[0][nf] = __builtin_amdgcn_mfma_f32_16x16x32_bf16(av0, bv, acc[0][nf], 0, 0, 0);
        acc[1][nf] = __builtin_amdgcn_mfma_f32_16x16x32_bf16(av1, bv, acc[1][nf], 0, 0, 0);
      }
    }
    __syncthreads();
    rA0 = nA0; rA1 = nA1; rW = nW; rB0 = nB0; rB1 = nB1; rWb = nWb;
  }

  const int col0 = lane & 15;
  unsigned short* GaS = (unsigned short*)smemraw;       // EP2: [128][68] bf16
  float* GmS = (float*)(smemraw + 17408);               // EP2: [4][64] f32
  float* red0 = (EP == 2) ? (float*)(smemraw + 18432) : (float*)smemraw;
  float* red1 = red0 + 256;

  if constexpr (EP == 2) {
    // write prefetched Ga tile + Gm rows to LDS (no global latency here)
#pragma unroll
    for (int p = 0; p < 4; ++p) {
      int i = tid + p * 256;
      int rl = i >> 3, sg = (i & 7) * 8;
      *(ushort8*)(GaS + rl * 68 + sg) = rGa[p];
    }
    GmS[tid] = gmv;
    __syncthreads();
  }

#pragma unroll
  for (int rf = 0; rf < 2; ++rf) {
    const int rbase = rf * 64 + w * 16 + (lane >> 4) * 4;
    if constexpr (EP == 0) {
#pragma unroll
      for (int nf = 0; nf < 4; ++nf) {
        int o = bo0 + nf * 16 + col0;
#pragma unroll
        for (int e = 0; e < 4; ++e)
          g.outf[(size_t)(br0 + rbase + e) * g.O + o] = acc[rf][nf][e];
      }
    }
    if constexpr (EP == 1) {
#pragma unroll
      for (int nf = 0; nf < 4; ++nf) {
        int o = bo0 + nf * 16 + col0;
        __hip_bfloat16* dst;
        int oc, ostr;
        if (g.outb2) {
          ostr = g.Oh;
          if (o >= g.Oh) { dst = g.outb2; oc = o - g.Oh; }
          else { dst = g.outb; oc = o; }
        } else {
          dst = g.outb; oc = o; ostr = g.O;
        }
#pragma unroll
        for (int e = 0; e < 4; ++e)
          dst[(size_t)(br0 + rbase + e) * ostr + oc] = __float2bfloat16(acc[rf][nf][e]);
      }
    }
    if constexpr (EP == 2 || EP == 3) {
      float vals[4][4];
#pragma unroll
      for (int nf = 0; nf < 4; ++nf) {
        int ol = nf * 16 + col0;
        int o = bo0 + ol;
#pragma unroll
        for (int e = 0; e < 4; ++e) {
          int rl = rbase + e;
          float v = acc[rf][nf][e];
          if constexpr (EP == 2) {
            v += b2f(GaS[rl * 68 + ol]) +
                 nxs[rl][0] * waxs[ol][0] + nxs[rl][1] * waxs[ol][1] +
                 nxs[rl][2] * waxs[ol][2] - GmS[((rl >> 5) << 6) + ol];
          }
          vals[nf][e] = v;
          if constexpr (EP == 2)
            g.outb[(size_t)(br0 + rl) * g.O + o] = __float2bfloat16(v);
          else
            g.outf[(size_t)(br0 + rl) * g.O + o] = v;
        }
      }
#pragma unroll
      for (int nf = 0; nf < 4; ++nf) {
        float s0 = vals[nf][0] + vals[nf][1] + vals[nf][2] + vals[nf][3];
        float s1 = vals[nf][0] * vals[nf][0] + vals[nf][1] * vals[nf][1] +
                   vals[nf][2] * vals[nf][2] + vals[nf][3] * vals[nf][3];
        s0 += __shfl_xor(s0, 16); s0 += __shfl_xor(s0, 32);
        s1 += __shfl_xor(s1, 16); s1 += __shfl_xor(s1, 32);
        if ((lane >> 4) == 0) {
          red0[w * 64 + nf * 16 + lane] = s0;
          red1[w * 64 + nf * 16 + lane] = s1;
        }
      }
      __syncthreads();
      if (tid < 64) {
        float t0 = red0[tid] + red0[64 + tid] + red0[128 + tid] + red0[192 + tid];
        float t1 = red1[tid] + red1[64 + tid] + red1[128 + tid] + red1[192 + tid];
        size_t base = ((size_t)(rt * 2 + rf) * g.numOt + ot) * 128;
        g.partial[base + tid] = t0;
        g.partial[base + 64 + tid] = t1;
      }
      __syncthreads();
    }
  }
}

// ================= fp combine: fp_pre = Gf[nbr] + nx.Wfx, + partials =================
__global__ __launch_bounds__(256) void combine_fp_kernel(
    const unsigned short* Gf, const float* Wf, int wk,
    const float* xyz, const float* ctr, const int* idx,
    __hip_bfloat16* fpout, float* partial, int numOt, int M, int Ncur, int O) {
  __shared__ float tile[64][68];
  __shared__ float nxs[64][3];
  __shared__ float wfx[64][3];
  __shared__ int grow[64];
  int tid = threadIdx.x;
  int rt = blockIdx.x, ot = blockIdx.y;
  int br0 = rt * 64, bo0 = ot * 64;
  if (tid < 64) {
    int r = br0 + tid;
    int bm = r >> 5;
    int b = bm / M;
    int n = idx[(size_t)bm * KN + (r & (KN - 1))];
    int nb = b * Ncur + n;
    grow[tid] = nb;
    nxs[tid][0] = xyz[(size_t)nb * 3 + 0] - ctr[(size_t)bm * 3 + 0];
    nxs[tid][1] = xyz[(size_t)nb * 3 + 1] - ctr[(size_t)bm * 3 + 1];
    nxs[tid][2] = xyz[(size_t)nb * 3 + 2] - ctr[(size_t)bm * 3 + 2];
  } else if (tid < 128) {
    int o = tid - 64;
    wfx[o][0] = Wf[(size_t)(bo0 + o) * wk + 0];
    wfx[o][1] = Wf[(size_t)(bo0 + o) * wk + 1];
    wfx[o][2] = Wf[(size_t)(bo0 + o) * wk + 2];
  }
  __syncthreads();
  int rr = tid >> 2, os = (tid & 3) * 16;
  const unsigned short* gr = Gf + (size_t)grow[rr] * O + bo0 + os;
  ushort8 v0 = *(const ushort8*)gr;
  ushort8 v1 = *(const ushort8*)(gr + 8);
  __hip_bfloat16* outp = fpout + (size_t)(br0 + rr) * O + bo0 + os;
  float nx0 = nxs[rr][0], nx1 = nxs[rr][1], nx2 = nxs[rr][2];
#pragma unroll
  for (int i = 0; i < 16; ++i) {
    float gv = b2f(i < 8 ? v0[i] : v1[i - 8]);
    int o = os + i;
    float val = gv + nx0 * wfx[o][0] + nx1 * wfx[o][1] + nx2 * wfx[o][2];
    tile[rr][o] = val;
    outp[i] = __float2bfloat16(val);
  }
  __syncthreads();
  if (tid < 64) {
    float s = 0.f, s2 = 0.f;
#pragma unroll 4
    for (int r2 = 0; r2 < 64; ++r2) {
      float v = tile[r2][tid];
      s += v; s2 += v * v;
    }
    size_t base = ((size_t)rt * numOt + ot) * 128;
    partial[base + tid] = s;
    partial[base + 64 + tid] = s2;
  }
}

// ================= fused bn+relu (in-place) + k-mean for fp buffer =================
// 256 threads = 4 bm-slabs per block (one per 64-lane group) for occupancy.
__global__ __launch_bounds__(256) void bn_fpmean_kernel(__hip_bfloat16* fp, const float2* stats2,
                                                        __hip_bfloat16* outm, int O) {
  int bm = blockIdx.x * 4 + (threadIdx.x >> 6);
  int o = blockIdx.y * 64 + (threadIdx.x & 63);
  float2 st = stats2[o];
  __hip_bfloat16* p = fp + (size_t)bm * KN * O + o;
  float s = 0.f;
#pragma unroll
  for (int kk = 0; kk < KN; ++kk) {
    float v = __bfloat162float(p[(size_t)kk * O]);
    float y = fmaxf((v - st.x) * st.y, 0.f);
    __hip_bfloat16 yb = __float2bfloat16(y);
    p[(size_t)kk * O] = yb;
    s += __bfloat162float(yb);
  }
  outm[(size_t)bm * O + o] = __float2bfloat16(s * (1.f / KN));
}

// ================= apply: bn+relu+softmax+weighted sum =================
// 256 threads = 4 bm per block (one per 64-lane group) for occupancy.
__global__ __launch_bounds__(256) void apply_lite_kernel(const __hip_bfloat16* alpha,
                                                         const __hip_bfloat16* fp,
                                                         const float2* stats2, float* fout, int O) {
  int bm = blockIdx.x * 4 + (threadIdx.x >> 6);
  int o = blockIdx.y * 64 + (threadIdx.x & 63);
  float2 st = stats2[o];
  size_t base = (size_t)bm * KN * O + o;
  float a[KN];
  float mx = -3.4e38f;
#pragma unroll
  for (int kk = 0; kk < KN; ++kk) {
    float v = fmaxf((__bfloat162float(alpha[base + (size_t)kk * O]) - st.x) * st.y, 0.f);
    a[kk] = v; mx = fmaxf(mx, v);
  }
  float s = 0.f;
#pragma unroll
  for (int kk = 0; kk < KN; ++kk) { float e = expf(a[kk] - mx); a[kk] = e; s += e; }
  float acc = 0.f;
#pragma unroll
  for (int kk = 0; kk < KN; ++kk) acc += a[kk] * __bfloat162float(fp[base + (size_t)kk * O]);
  fout[(size_t)bm * O + o] = acc / s;
}

// ================= fp32 dense GEMM (SPFE / head2) =================
struct GemmArgs {
  const float* A; const float* W; const float* bias;
  float* out; __hip_bfloat16* outb;
  float* partial; const float2* stats2; float* fout;
  const __hip_bfloat16* fpb; const float* fpmean;
  const float* xyz; const float* feat; const float* ctr; const int* idx; const float* bmean;
  int R, K, O, numOt, M, Cf, Of, Ncur;
};

template <int EMODE, int MODE>
__global__ __launch_bounds__(256) void gemm_dense(GemmArgs g) {
  __shared__ float smem[2 * BKK * ASTR];
  float* As = smem;
  float* Ws = smem + BKK * ASTR;
  const int tid = threadIdx.x;
  const int tr = tid >> 4, tc = tid & 15;
  const int rt = blockIdx.x, ot = blockIdx.y;
  const int br0 = rt * BR, bo0 = ot * BO;
  float acc[4][4] = {};
  for (int k0 = 0; k0 < g.K; k0 += BKK) {
    for (int i = tid; i < BR * BKK; i += 256) {
      int rr = i >> 4, cc = i & 15;
      int c = k0 + cc;
      float v = 0.f;
      if (c < g.K) {
        if constexpr (MODE == 0) {
          v = g.A[(size_t)(br0 + rr) * g.K + c];
        } else {
          int r = br0 + rr;
          int b = r / g.Ncur, n = r - b * g.Ncur;
          if (c < 3) v = g.xyz[((size_t)b * g.Ncur + n) * 3 + c];
          else if (c < 6) v = g.xyz[((size_t)b * g.Ncur + n) * 3 + (c - 3)] - g.bmean[b * 3 + (c - 3)];
        }
      }
      As[cc * ASTR + rr] = v;
    }
    for (int i = tid; i < BO * BKK; i += 256) {
      int oo = i >> 4, cc = i & 15;
      int o = bo0 + oo, c = k0 + cc;
      Ws[cc * ASTR + oo] = (o < g.O && c < g.K) ? g.W[(size_t)o * g.K + c] : 0.f;
    }
    __syncthreads();
#pragma unroll
    for (int kk = 0; kk < BKK; ++kk) {
      float a0[4], w0[4];
#pragma unroll
      for (int i = 0; i < 4; ++i) a0[i] = As[kk * ASTR + tr * 4 + i];
#pragma unroll
      for (int j = 0; j < 4; ++j) w0[j] = Ws[kk * ASTR + tc * 4 + j];
#pragma unroll
      for (int i = 0; i < 4; ++i)
#pragma unroll
        for (int j = 0; j < 4; ++j) acc[i][j] += a0[i] * w0[j];
    }
    __syncthreads();
  }
#pragma unroll
  for (int i = 0; i < 4; ++i) {
    int r = br0 + tr * 4 + i;
    if (r >= g.R) continue;
#pragma unroll
    for (int j = 0; j < 4; ++j) {
      int o = bo0 + tc * 4 + j;
      if (o >= g.O) continue;
      float v = acc[i][j];
      if (EMODE == 0 && g.bias) v += g.bias[o];
      g.out[(size_t)r * g.O + o] = v;
    }
  }
  if constexpr (EMODE == 1) {
    float* red0 = smem;
    float* red1 = smem + 1024;
#pragma unroll
    for (int j = 0; j < 4; ++j) {
      float s0 = 0.f, s1 = 0.f;
#pragma unroll
      for (int i = 0; i < 4; ++i) { float v = acc[i][j]; s0 += v; s1 += v * v; }
      red0[tr * 64 + tc * 4 + j] = s0;
      red1[tr * 64 + tc * 4 + j] = s1;
    }
    __syncthreads();
    for (int st = 8; st >= 1; st >>= 1) {
      if (tr < st) {
#pragma unroll
        for (int j = 0; j < 4; ++j) {
          int cix = tc * 4 + j;
          red0[tr * 64 + cix] += red0[(tr + st) * 64 + cix];
          red1[tr * 64 + cix] += red1[(tr + st) * 64 + cix];
        }
      }
      __syncthreads();
    }
    if (tr == 0) {
      size_t base = ((size_t)rt * g.numOt + ot) * 128;
#pragma unroll
      for (int j = 0; j < 4; ++j) {
        int cix = tc * 4 + j;
        g.partial[base + cix] = red0[cix];
        g.partial[base + 64 + cix] = red1[cix];
      }
    }
  }
}

// ================= stats / bn =================
__global__ void reduce_finalize_kernel(const float* partial, float2* stats2,
                                       int Rt, int numOt, int R, int O) {
  int o = blockIdx.x;
  int ot = o >> 6, oo = o & 63;
  int tid = threadIdx.x;
  double s = 0.0, s2 = 0.0;
  for (int rtt = tid; rtt < Rt; rtt += 256) {
    const float* p = partial + ((size_t)rtt * numOt + ot) * 128;
    s += (double)p[oo];
    s2 += (double)p[64 + oo];
  }
  __shared__ double r0[256], r1[256];
  r0[tid] = s; r1[tid] = s2;
  __syncthreads();
  for (int st = 128; st > 0; st >>= 1) {
    if (tid < st) { r0[tid] += r0[tid + st]; r1[tid] += r1[tid + st]; }
    __syncthreads();
  }
  if (tid == 0) {
    double mu = r0[0] / R;
    double var = r1[0] / R - mu * mu;
    stats2[o] = make_float2((float)mu, 1.f / sqrtf((float)var + EPSV));
  }
}

template <bool BF16>
__global__ void bn_apply_relu_kernel(void* xv, const float2* stats2, long long tot, int C) {
  float* xf = (float*)xv;
  __hip_bfloat16* xb = (__hip_bfloat16*)xv;
  for (long long gidx = (long long)blockIdx.x * blockDim.x + threadIdx.x; gidx < tot;
       gidx += (long long)gridDim.x * blockDim.x) {
    int c = (int)(gidx % C);
    float2 st = stats2[c];
    float v = BF16 ? __bfloat162float(xb[gidx]) : xf[gidx];
    float y = fmaxf((v - st.x) * st.y, 0.f);
    if (BF16) xb[gidx] = __float2bfloat16(y);
    else xf[gidx] = y;
  }
}

// ================= misc =================
__global__ void mean_xyz_kernel(const float* xyz, float* bmean, int N) {
  int b = blockIdx.x, tid = threadIdx.x;
  __shared__ float s[3][256];
  float sx = 0, sy = 0, sz = 0;
  for (int n = tid; n < N; n += 256) {
    const float* p = xyz + ((size_t)b * N + n) * 3;
    sx += p[0]; sy += p[1]; sz += p[2];
  }
  s[0][tid] = sx; s[1][tid] = sy; s[2][tid] = sz;
  __syncthreads();
  for (int st = 128; st > 0; st >>= 1) {
    if (tid < st) {
      s[0][tid] += s[0][tid + st];
      s[1][tid] += s[1][tid + st];
      s[2][tid] += s[2][tid + st];
    }
    __syncthreads();
  }
  if (tid < 3) bmean[b * 3 + tid] = s[tid][0] / (float)N;
}

__global__ void centers_kernel(const float* xyz, float* ctr, int B, int N, int M) {
  int g = blockIdx.x * blockDim.x + threadIdx.x;
  if (g >= B * M) return;
  int b = g / M, m = g % M;
  float delta = (float)(N - 1) / (float)(M - 1);
  int n = (int)((float)m * delta);
  if (n > N - 1) n = N - 1;
  ctr[(size_t)g * 3 + 0] = xyz[((size_t)b * N + n) * 3 + 0];
  ctr[(size_t)g * 3 + 1] = xyz[((size_t)b * N + n) * 3 + 1];
  ctr[(size_t)g * 3 + 2] = xyz[((size_t)b * N + n) * 3 + 2];
}

// KNN with per-lane sorted top-4 head lists (verified R15; 16-wave blocks verified R22)
__global__ __launch_bounds__(1024) void knn_heads_kernel(const float* xyz, const float* ctr,
                                                         int* idx_out, int B, int N, int M) {
  extern __shared__ float sm[];
  const int pitch = N + (N >> 6);
  float* xs = sm;
  float* ys = sm + pitch;
  float* zs = sm + 2 * pitch;
  const int b = blockIdx.y;
  const int tid = threadIdx.x;
  const float* xb = xyz + (size_t)b * N * 3;
  for (int i = tid; i < N; i += blockDim.x) {
    int pi = i + (i >> 6);
    xs[pi] = xb[i * 3 + 0];
    ys[pi] = xb[i * 3 + 1];
    zs[pi] = xb[i * 3 + 2];
  }
  __syncthreads();
  const int w = tid >> 6, lane = tid & 63;
  const int wpb = blockDim.x >> 6;
  const int m = blockIdx.x * wpb + w;
  if (m >= M) return;
  const int bm = b * M + m;
  const float cx = ctr[(size_t)bm * 3], cy = ctr[(size_t)bm * 3 + 1], cz = ctr[(size_t)bm * 3 + 2];
  const float cc = cx * cx + cy * cy + cz * cz;
  const int npl = N >> 6;
  const int shift = 31 - __clz(npl);
  const int base = lane * npl;
  const int pb = base + (base >> 6);
  const float INF = 3.4e38f;
  const int IMAX = 0x7fffffff;

  float a0 = INF, a1 = INF, a2 = INF, a3 = INF;
  int i0 = IMAX, i1 = IMAX, i2 = IMAX, i3 = IMAX;
  for (int j = 0; j < npl; ++j) {
    float x = xs[pb + j], y = ys[pb + j], z = zs[pb + j];
    float d2 = cc + (x * x + y * y + z * z) - 2.f * (cx * x + cy * y + cz * z);
    int gj = base + j;
    bool lt0 = (d2 < a0) || (d2 == a0 && gj < i0);
    bool lt1 = (d2 < a1) || (d2 == a1 && gj < i1);
    bool lt2 = (d2 < a2) || (d2 == a2 && gj < i2);
    bool lt3 = (d2 < a3) || (d2 == a3 && gj < i3);
    float na3 = lt2 ? a2 : (lt3 ? d2 : a3); int ni3 = lt2 ? i2 : (lt3 ? gj : i3);
    float na2 = lt1 ? a1 : (lt2 ? d2 : a2); int ni2 = lt1 ? i1 : (lt2 ? gj : i2);
    float na1 = lt0 ? a0 : (lt1 ? d2 : a1); int ni1 = lt0 ? i0 : (lt1 ? gj : i1);
    float na0 = lt0 ? d2 : a0;              int ni0 = lt0 ? gj : i0;
    a0 = na0; a1 = na1; a2 = na2; a3 = na3;
    i0 = ni0; i1 = ni1; i2 = ni2; i3 = ni3;
  }

  unsigned int rmlo = 0u, rmhi = 0u;
  int remaining = npl;

  for (int sel = 0; sel < KN; ++sel) {
    float d = a0;
    int ii = i0;
#pragma unroll
    for (int off = 1; off < 64; off <<= 1) {
      float od = __shfl_xor(d, off);
      int oi = __shfl_xor(ii, off);
      if (od < d || (od == d && oi < ii)) { d = od; ii = oi; }
    }
    if (lane == 0) idx_out[(size_t)bm * KN + sel] = ii;
    const int owner = ii >> shift;
    if (lane == owner) {
      int jin = ii - (owner << shift);
      if (jin < 32) rmlo |= 1u << jin;
      else rmhi |= 1u << (jin - 32);
      remaining--;
      a0 = a1; i0 = i1; a1 = a2; i1 = i2; a2 = a3; i2 = i3;
      a3 = INF; i3 = IMAX;
    }
    if (sel == KN - 1) break;
    float h = __shfl(a0, owner);
    int remo = __shfl(remaining, owner);
    if (h >= INF && remo > 0) {
      unsigned int olo = __shfl(rmlo, owner);
      unsigned int ohi = __shfl(rmhi, owner);
      const int obase = owner << shift;
      const int opb = obase + (obase >> 6);
      float c0 = INF, c1 = INF, c2 = INF, c3 = INF;
      int jc0 = IMAX, jc1 = IMAX, jc2 = IMAX, jc3 = IMAX;
      if (lane < npl) {
        bool rem = (lane < 32) ? ((olo >> lane) & 1u) : ((ohi >> (lane - 32)) & 1u);
        if (!rem) {
          float x = xs[opb + lane], y = ys[opb + lane], z = zs[opb + lane];
          c0 = cc + (x * x + y * y + z * z) - 2.f * (cx * x + cy * y + cz * z);
          jc0 = obase + lane;
        }
      }
#pragma unroll
      for (int off = 1; off < 64; off <<= 1) {
        float b0v = __shfl_xor(c0, off), b1v = __shfl_xor(c1, off);
        float b2v = __shfl_xor(c2, off), b3v = __shfl_xor(c3, off);
        int d0v = __shfl_xor(jc0, off), d1v = __shfl_xor(jc1, off);
        int d2v = __shfl_xor(jc2, off), d3v = __shfl_xor(jc3, off);
        bool t1 = (c0 < b0v) || (c0 == b0v && jc0 < d0v);
        float o0 = t1 ? c0 : b0v; int p0 = t1 ? jc0 : d0v;
        float A0 = t1 ? c1 : c0, A1 = t1 ? c2 : c1, A2 = t1 ? c3 : c2;
        int IA0 = t1 ? jc1 : jc0, IA1 = t1 ? jc2 : jc1, IA2 = t1 ? jc3 : jc2;
        float B0 = t1 ? b0v : b1v, B1 = t1 ? b1v : b2v, B2 = t1 ? b2v : b3v;
        int IB0 = t1 ? d0v : d1v, IB1 = t1 ? d1v : d2v, IB2 = t1 ? d2v : d3v;
        bool t2 = (A0 < B0) || (A0 == B0 && IA0 < IB0);
        float o1 = t2 ? A0 : B0; int p1 = t2 ? IA0 : IB0;
        float A0b = t2 ? A1 : A0, A1b = t2 ? A2 : A1;
        int IA0b = t2 ? IA1 : IA0, IA1b = t2 ? IA2 : IA1;
        float B0b = t2 ? B0 : B1, B1b = t2 ? B1 : B2;
        int IB0b = t2 ? IB0 : IB1, IB1b = t2 ? IB1 : IB2;
        bool t3 = (A0b < B0b) || (A0b == B0b && IA0b < IB0b);
        float o2 = t3 ? A0b : B0b; int p2 = t3 ? IA0b : IB0b;
        float A0c = t3 ? A1b : A0b; int IA0c = t3 ? IA1b : IA0b;
        float B0c = t3 ? B0b : B1b; int IB0c = t3 ? IB0b : IB1b;
        bool t4 = (A0c < B0c) || (A0c == B0c && IA0c < IB0c);
        float o3 = t4 ? A0c : B0c; int p3 = t4 ? IA0c : IB0c;
        c0 = o0; c1 = o1; c2 = o2; c3 = o3;
        jc0 = p0; jc1 = p1; jc2 = p2; jc3 = p3;
      }
      if (lane == owner) {
        a0 = c0; a1 = c1; a2 = c2; a3 = c3;
        i0 = jc0; i1 = jc1; i2 = jc2; i3 = jc3;
      }
    }
  }
}

// interp3, 4 scanners per low-res point (verified R14)
__global__ __launch_bounds__(256) void interp3_par_kernel(const float* xl, const float* xh,
                                                          int* idx3, float* w3, int Nl, int Nh) {
  extern __shared__ float sm[];
  float* xs = sm;
  float* ys = sm + Nh;
  float* zs = sm + 2 * Nh;
  const int b = blockIdx.y;
  const int tid = threadIdx.x;
  const float* xb = xh + (size_t)b * Nh * 3;
  for (int i = tid; i < Nh; i += 256) {
    xs[i] = xb[i * 3 + 0];
    ys[i] = xb[i * 3 + 1];
    zs[i] = xb[i * 3 + 2];
  }
  __syncthreads();
  const int pt = tid >> 2, sc = tid & 3;
  const int l = blockIdx.x * 64 + pt;
  if (l >= Nl) return;
  const size_t g = (size_t)b * Nl + l;
  const float px = xl[g * 3], py = xl[g * 3 + 1], pz = xl[g * 3 + 2];
  const float pp = px * px + py * py + pz * pz;
  const int chunk = Nh >> 2;
  const int j0 = sc * chunk, j1 = j0 + chunk;
  float a0 = 3.4e38f, a1 = 3.4e38f, a2 = 3.4e38f;
  int i0 = 0x7fffffff, i1 = 0x7fffffff, i2 = 0x7fffffff;
  for (int j = j0; j < j1; ++j) {
    float x = xs[j], y = ys[j], z = zs[j];
    float d2 = (pp + (x * x + y * y + z * z)) - 2.f * (px * x + py * y + pz * z);
    if (d2 < a0) {
      a2 = a1; i2 = i1; a1 = a0; i1 = i0; a0 = d2; i0 = j;
    } else if (d2 < a1) {
      a2 = a1; i2 = i1; a1 = d2; i1 = j;
    } else if (d2 < a2) {
      a2 = d2; i2 = j;
    }
  }
#pragma unroll
  for (int off = 1; off < 4; off <<= 1) {
    float b0 = __shfl_xor(a0, off), b1 = __shfl_xor(a1, off), b2 = __shfl_xor(a2, off);
    int c0 = __shfl_xor(i0, off), c1 = __shfl_xor(i1, off), c2 = __shfl_xor(i2, off);
    bool t = (a0 < b0) || (a0 == b0 && i0 < c0);
    float o0 = t ? a0 : b0; int oi0 = t ? i0 : c0;
    float na0 = t ? a1 : a0, na1 = t ? a2 : a1;
    int nia0 = t ? i1 : i0, nia1 = t ? i2 : i1;
    float nb0 = t ? b0 : b1, nb1 = t ? b1 : b2;
    int nib0 = t ? c0 : c1, nib1 = t ? c1 : c2;
    bool t2 = (na0 < nb0) || (na0 == nb0 && nia0 < nib0);
    float o1 = t2 ? na0 : nb0; int oi1 = t2 ? nia0 : nib0;
    float ma0 = t2 ? na1 : na0; int mia0 = t2 ? nia1 : nia0;
    float mb0 = t2 ? nb0 : nb1; int mib0 = t2 ? nib0 : nib1;
    bool t3 = (ma0 < mb0) || (ma0 == mb0 && mia0 < mib0);
    float o2 = t3 ? ma0 : mb0; int oi2 = t3 ? mia0 : mib0;
    a0 = o0; a1 = o1; a2 = o2; i0 = oi0; i1 = oi1; i2 = oi2;
  }
  if (sc == 0) {
    float d0 = fmaxf(sqrtf(fmaxf(a0, 0.f)), 1e-8f);
    float d1 = fmaxf(sqrtf(fmaxf(a1, 0.f)), 1e-8f);
    float d2_ = fmaxf(sqrtf(fmaxf(a2, 0.f)), 1e-8f);
    float w0 = 1.f / d0, w1 = 1.f / d1, w2 = 1.f / d2_;
    float s = w0 + w1 + w2;
    idx3[g * 3 + 0] = i0;
    idx3[g * 3 + 1] = i1;
    idx3[g * 3 + 2] = i2;
    w3[g * 3 + 0] = w0 / s;
    w3[g * 3 + 1] = w1 / s;
    w3[g * 3 + 2] = w2 / s;
  }
}

__global__ void buildx_kernel(const float* fh, const float* fl, const int* idx3, const float* w3,
                              float* xout, int B, int Nl, int Nh, int Ch, int Cl) {
  int Cx = Ch + Cl;
  size_t tot = (size_t)B * Nl * Cx;
  for (size_t g = (size_t)blockIdx.x * blockDim.x + threadIdx.x; g < tot;
       g += (size_t)gridDim.x * blockDim.x) {
    int r = (int)(g / Cx), c = (int)(g % Cx);
    int b = r / Nl;
    if (c < Ch) {
      float s = 0.f;
      for (int j = 0; j < 3; ++j) {
        int n = idx3[(size_t)r * 3 + j];
        s += w3[(size_t)r * 3 + j] * fh[((size_t)b * Nh + n) * Ch + c];
      }
      xout[g] = s;
    } else {
      xout[g] = fl[(size_t)r * Cl + (c - Ch)];
    }
  }
}

// ================= host =================
extern "C" void kernel_launch(void* const* d_in, const int* in_sizes, int n_in,
                              void* d_out, int out_size, void* d_ws, size_t ws_size,
                              hipStream_t stream) {
  const int B = 8, N = 4096;
  const float* X = (const float*)d_in[0];
  const float* W_spfe1 = (const float*)d_in[1];
  const float* W_spfe2 = (const float*)d_in[3];
  const float* Wf1 = (const float*)d_in[5];
  const float* Wa1 = (const float*)d_in[7];
  const float* Wf2 = (const float*)d_in[9];
  const float* Wa2 = (const float*)d_in[11];
  const float* Wf3 = (const float*)d_in[13];
  const float* Wa3 = (const float*)d_in[15];
  const float* Wfp3 = (const float*)d_in[17];
  const float* Wfp2 = (const float*)d_in[19];
  const float* Wfp1 = (const float*)d_in[21];
  const float* Wh1 = (const float*)d_in[23];
  const float* Wh2 = (const float*)d_in[25];
  const float* bh2 = (const float*)d_in[26];
  float* out = (float*)d_out;

  char* wp = (char*)d_ws;
  auto alloc = [&](size_t bytes) -> void* {
    void* p = (void*)wp;
    wp += (bytes + 255) & ~(size_t)255;
    return p;
  };
  float2* stats2 = (float2*)alloc(512 * sizeof(float2) * 2);
  float* partial = (float*)alloc((size_t)8192 * 128 * 4);
  float* bmean = (float*)alloc(B * 3 * sizeof(float));
  float* f0 = (float*)alloc((size_t)B * N * 64 * 4);
  float* xyz1 = (float*)alloc((size_t)B * 1024 * 3 * 4);
  float* xyz2 = (float*)alloc((size_t)B * 512 * 3 * 4);
  float* xyz3 = (float*)alloc((size_t)B * 256 * 3 * 4);
  float* f1 = (float*)alloc((size_t)B * 1024 * 128 * 4);
  float* f2 = (float*)alloc((size_t)B * 512 * 256 * 4);
  float* f3 = (float*)alloc((size_t)B * 256 * 512 * 4);
  float* fpmean = (float*)alloc((size_t)B * 1024 * 128 * 4);
  __hip_bfloat16* fpmeanb = (__hip_bfloat16*)alloc((size_t)B * 1024 * 128 * 2);
  int* idxb = (int*)alloc((size_t)B * 1024 * KN * 4);
  int* idx3 = (int*)alloc((size_t)B * 4096 * 3 * 4);
  float* w3 = (float*)alloc((size_t)B * 4096 * 3 * 4);
  void* BIG = alloc((size_t)33554432 * 2);  // 64 MB: fp bf16 / f32 scratch
  size_t fup_off = (size_t)(wp - (char*)d_ws);
  float* fup2 = (float*)alloc((size_t)B * 512 * 256 * 4);
  float* fup1 = (float*)alloc((size_t)B * 1024 * 128 * 4);
  float* fup0 = (float*)alloc((size_t)B * 4096 * 128 * 4);
  // alpha aliases the fup region (disjoint lifetimes), 64 MB
  __hip_bfloat16* alphaBuf_all = (__hip_bfloat16*)((char*)d_ws + fup_off);
  size_t alpha_end = fup_off + (size_t)67108864;
  char* wp2 = (char*)d_ws + alpha_end;
  if (wp2 < wp) wp2 = wp;
  __hip_bfloat16* Gfb = (__hip_bfloat16*)wp2; wp2 += (size_t)8 * 1024 * 1024;
  __hip_bfloat16* Gab = (__hip_bfloat16*)wp2; wp2 += (size_t)8 * 1024 * 1024;
  float* Gm = (float*)wp2; wp2 += (size_t)4 * 1024 * 1024;
  __hip_bfloat16* Wbuf = (__hip_bfloat16*)wp2; wp2 += (size_t)2 * 1024 * 1024;  // bf16 W repack

  auto run_stats = [&](int R, int O) {
    reduce_finalize_kernel<<<O, 256, 0, stream>>>(partial, stats2, R / 64, O / 64, R, O);
  };
  auto run_bn = [&](void* x, int R, int C, bool bf) {
    long long tot = (long long)R * C;
    int blocks = (int)((tot + 255) / 256);
    if (blocks > 4096) blocks = 4096;
    if (bf) bn_apply_relu_kernel<true><<<blocks, 256, 0, stream>>>(x, stats2, tot, C);
    else bn_apply_relu_kernel<false><<<blocks, 256, 0, stream>>>(x, stats2, tot, C);
  };
  auto run_knn = [&](const float* xyz_in, const float* ctr, int Nc, int M) {
    int pitch = Nc + (Nc >> 6);
    size_t sm = (size_t)3 * pitch * 4;
    int wpb = ((M % 16) == 0) ? 16 : 4;
    knn_heads_kernel<<<dim3(M / wpb, B), wpb * 64, sm, stream>>>(xyz_in, ctr, idxb, B, Nc, M);
  };
  auto run_convw = [&](const float* W, int wk, int colOff, int O, int K, __hip_bfloat16* dst) {
    long long tot = (long long)O * K;
    convw_kernel<<<(int)((tot + 255) / 256), 256, 0, stream>>>(W, dst, wk, colOff, tot, K);
  };

  // ---- SPFE (fp32, small K) ----
  mean_xyz_kernel<<<B, 256, 0, stream>>>(X, bmean, N);
  float* hbuf = (float*)BIG;
  {
    GemmArgs g{};
    g.W = W_spfe1; g.out = hbuf; g.partial = partial;
    g.R = B * N; g.K = 9; g.O = 64; g.numOt = 1;
    g.xyz = X; g.bmean = bmean; g.Ncur = N;
    gemm_dense<1, 3><<<dim3(g.R / 64, 1), 256, 0, stream>>>(g);
    run_stats(g.R, g.O); run_bn(hbuf, g.R, g.O, false);
  }
  {
    GemmArgs g{};
    g.A = hbuf; g.W = W_spfe2; g.out = f0; g.partial = partial;
    g.R = B * N; g.K = 64; g.O = 64; g.numOt = 1;
    gemm_dense<1, 0><<<dim3(g.R / 64, 1), 256, 0, stream>>>(g);
    run_stats(g.R, g.O); run_bn(f0, g.R, g.O, false);
  }

  // ---- SA path (dense decomposed, pipelined GEMM, bf16-W, fused bn+fpmean) ----
  auto sa = [&](const float* xyz_in, const float* feat_in, int Nc, int M, int Cf, int Of,
                const float* Wf, const float* Wa, float* xyz_out, float* f_out) {
    int BM = B * M, R = BM * KN, NR = B * Nc;
    int wkF = 3 + Cf, wkA = 3 + Cf + Of;
    centers_kernel<<<ceil_div(BM, 256), 256, 0, stream>>>(xyz_in, xyz_out, B, Nc, M);
    run_knn(xyz_in, xyz_out, Nc, M);
    __hip_bfloat16* fpbuf = (__hip_bfloat16*)BIG;
    {  // [Gf | Ga] = feat . [Wf[:,3:3+Cf] ; Wa[:,3:3+Cf]]  (fused: one A pass)
      run_convw(Wf, wkF, 3, Of, Cf, Wbuf);
      run_convw(Wa, wkA, 3, Of, Cf, Wbuf + (size_t)Of * Cf);
      MdArgs m{}; m.Af = feat_in; m.lda = Cf;
      m.Wb = (const unsigned short*)Wbuf;
      m.R = NR; m.K = Cf; m.O = 2 * Of; m.Oh = Of;
      m.outb = Gfb; m.outb2 = Gab; m.numOt = (2 * Of) / 64;
      gemm_mdw<1, false, true><<<dim3(((2 * Of) / 64) * (NR / 128)), 256, 0, stream>>>(m);
    }
    combine_fp_kernel<<<dim3(R / 64, Of / 64), 256, 0, stream>>>(
        (const unsigned short*)Gfb, Wf, wkF, xyz_in, xyz_out, idxb, fpbuf,
        partial, Of / 64, M, Nc, Of);
    run_stats(R, Of);
    bn_fpmean_kernel<<<dim3(BM / 4, Of / 64), 256, 0, stream>>>(fpbuf, stats2, fpmeanb, Of);
    // WaP repack shared by Gm and alpha
    run_convw(Wa, wkA, 3 + Cf, Of, Of, Wbuf);
    {  // Gm = fpmean . Wa[:,3+Cf:]
      MdArgs m{}; m.Ab = (const unsigned short*)fpmeanb; m.lda = Of; m.W = Wa; m.wk = wkA;
      m.colOff = 3 + Cf; m.Wb = (const unsigned short*)Wbuf;
      m.R = BM; m.K = Of; m.O = Of; m.outf = Gm; m.numOt = Of / 64;
      gemm_mdw<0, true, true><<<dim3((Of / 64) * (BM / 128)), 256, 0, stream>>>(m);
    }
    {  // alpha = fp . Wa_p + Ga[nbr] + nx.Wa_x - Gm[bm]  (+ partials)
      MdArgs m{}; m.Ab = (const unsigned short*)fpbuf; m.lda = Of; m.W = Wa; m.wk = wkA;
      m.colOff = 3 + Cf; m.Wb = (const unsigned short*)Wbuf;
      m.R = R; m.K = Of; m.O = Of;
      m.outb = alphaBuf_all; m.partial = partial; m.numOt = Of / 64;
      m.Ga = (const unsigned short*)Gab; m.Gm = Gm;
      m.xyz = xyz_in; m.ctr = xyz_out; m.idx = idxb; m.M = M; m.Ncur = Nc;
      gemm_mdw<2, true, true><<<dim3((Of / 64) * (R / 128)), 256, 0, stream>>>(m);
    }
    run_stats(R, Of);
    apply_lite_kernel<<<dim3(BM / 4, Of / 64), 256, 0, stream>>>(alphaBuf_all, fpbuf, stats2, f_out, Of);
  };

  sa(X, f0, 4096, 1024, 64, 128, Wf1, Wa1, xyz1, f1);
  sa(xyz1, f1, 1024, 512, 128, 256, Wf2, Wa2, xyz2, f2);
  sa(xyz2, f2, 512, 256, 256, 512, Wf3, Wa3, xyz3, f3);

  // ---- FP layers (bf16 MFMA wide, EP3, bf16-W) ----
  auto fpl = [&](const float* xl, const float* xh, const float* fl, const float* fh,
                 int Nl, int Nh, int Cl, int Ch, const float* W, float* f_up, int O) {
    size_t smI = (size_t)3 * Nh * 4;
    interp3_par_kernel<<<dim3(ceil_div(Nl, 64), B), 256, smI, stream>>>(xl, xh, idx3, w3, Nl, Nh);
    float* xbuf = (float*)BIG;
    int Cx = Ch + Cl;
    size_t tot = (size_t)B * Nl * Cx;
    int blocks = (int)((tot + 255) / 256);
    if (blocks > 4096) blocks = 4096;
    buildx_kernel<<<blocks, 256, 0, stream>>>(fh, fl, idx3, w3, xbuf, B, Nl, Nh, Ch, Cl);
    run_convw(W, Cx, 0, O, Cx, Wbuf);
    MdArgs m{};
    m.Af = xbuf; m.lda = Cx; m.W = W; m.wk = Cx; m.colOff = 0;
    m.R = B * Nl; m.K = Cx; m.O = O;
    m.Wb = (const unsigned short*)Wbuf;
    m.outf = f_up; m.partial = partial; m.numOt = O / 64;
    gemm_mdw<3, false, true><<<dim3((O / 64) * (m.R / 128)), 256, 0, stream>>>(m);
    run_stats(m.R, O); run_bn(f_up, m.R, O, false);
  };

  fpl(xyz2, xyz3, f2, f3, 512, 256, 256, 512, Wfp3, fup2, 256);
  fpl(xyz1, xyz2, f1, fup2, 1024, 512, 128, 256, Wfp2, fup1, 128);
  fpl(X, xyz1, f0, fup1, 4096, 1024, 64, 128, Wfp1, fup0, 128);

  // ---- head ----
  float* hh = (float*)BIG;
  {
    run_convw(Wh1, 128, 0, 128, 128, Wbuf);
    MdArgs m{};
    m.Af = fup0; m.lda = 128; m.W = Wh1; m.wk = 128; m.colOff = 0;
    m.Wb = (const unsigned short*)Wbuf;
    m.R = B * N; m.K = 128; m.O = 128;
    m.outf = hh; m.partial = partial; m.numOt = 2;
    gemm_mdw<3, false, true><<<dim3(2 * (m.R / 128)), 256, 0, stream>>>(m);
    run_stats(m.R, m.O); run_bn(hh, m.R, m.O, false);
  }
  {
    GemmArgs g{};
    g.A = hh; g.W = Wh2; g.bias = bh2; g.out = out;
    g.R = B * N; g.K = 128; g.O = 50; g.numOt = 1;
    gemm_dense<0, 0><<<dim3(g.R / 64, 1), 256, 0, stream>>>(g);
  }
}

// Round 29
// 919.315 us; speedup vs baseline: 1.0307x; 1.0162x over previous
//
#include <hip/hip_runtime.h>
#include <hip/hip_bf16.h>
#include <cstdint>
#include <cstddef>

#define KN 32
#define EPSV 1e-5f
#define BR 64
#define BO 64
#define BKK 16
#define ASTR 68   // fp32 LDS tile stride (dense fp32 kernel)
#define BKM 32    // mfma K-chunk
#define BKP 40    // bf16 LDS row stride in shorts (80B: 16B-aligned, bank-spread)

typedef float f32x4 __attribute__((ext_vector_type(4)));
typedef __bf16 bf16x8 __attribute__((ext_vector_type(8)));
typedef unsigned short ushort8 __attribute__((ext_vector_type(8)));

static inline int ceil_div(int a, int b) { return (a + b - 1) / b; }

__device__ __forceinline__ float b2f(unsigned short u) {
  union { float f; uint32_t i; } x;
  x.i = (uint32_t)u << 16;
  return x.f;
}

__device__ __forceinline__ unsigned short f2bu(float f) {
  __hip_bfloat16 h = __float2bfloat16(f);
  union { __hip_bfloat16 h; unsigned short u; } c;
  c.h = h;
  return c.u;
}

// ================= fp32 -> bf16 row-major W repack =================
__global__ void convw_kernel(const float* W, __hip_bfloat16* Wb, int wk, int colOff,
                             long long tot, int K) {
  long long i = (long long)blockIdx.x * blockDim.x + threadIdx.x;
  if (i >= tot) return;
  int o = (int)(i / K), c = (int)(i % K);
  Wb[i] = __float2bfloat16(W[(size_t)o * wk + colOff + c]);
}

// ================= wide (128-row) dense bf16-MFMA GEMM =================
// R17 tile + R21 XCD swizzle + R23 pipelined staging + R26 Ga/Gm reg prefetch
// + R28 dual-chunk barrier pair. R29: optional fused bn+relu on the fp32
// A-staging path (ABN): y = max((v-mu)*rstd, 0) applied in f32 before f2bu --
// bit-identical to the standalone bn_apply_relu pass it replaces.
struct MdArgs {
  const float* Af; const unsigned short* Ab; int lda;
  const float* W; int wk; int colOff;
  const unsigned short* Wb;   // dense bf16 [O][K] repack (WBF16 path)
  const float2* bnstA;        // ABN: per-K-channel (mu, rstd)
  float* outf; __hip_bfloat16* outb;
  __hip_bfloat16* outb2; int Oh;   // EP1 split store (fused Gf|Ga)
  float* partial; int numOt;
  const unsigned short* Ga; const float* Gm;
  const float* xyz; const float* ctr; const int* idx;
  int M, Ncur;
  int R, K, O;
};

template <int EP, bool ABF16, bool WBF16, bool ABN>
__global__ __launch_bounds__(256) void gemm_mdw(MdArgs g) {
  constexpr int SMEMB = 384 * BKP * 2;   // [A0|W0|A1|W1] = 30720 B; EP2 reuse (20480) fits
  __shared__ __align__(16) char smemraw[SMEMB];
  __shared__ float nxs[128][3];
  __shared__ float waxs[64][3];
  __shared__ int grow[128];
  __hip_bfloat16* As = (__hip_bfloat16*)smemraw;        // chunk a: A[128][BKP]
  __hip_bfloat16* Ws = As + 128 * BKP;                  // chunk a: W[64][BKP]
  __hip_bfloat16* As2 = As + 192 * BKP;                 // chunk b: A[128][BKP]
  __hip_bfloat16* Ws2 = As + 320 * BKP;                 // chunk b: W[64][BKP]
  const int tid = threadIdx.x;
  const int lane = tid & 63, w = tid >> 6;
  // XCD-aware decode: per-XCD contiguous rt-slab, ot fastest within the slab.
  const int cpx = gridDim.x >> 3;
  const int s = (blockIdx.x & 7) * cpx + (blockIdx.x >> 3);
  const int rt = s / g.numOt;
  const int ot = s - rt * g.numOt;
  const int br0 = rt * 128, bo0 = ot * BO;

  ushort8 rGa[4];
  float gmv;
  if constexpr (EP == 2) {
    if (tid < 128) {
      int r = br0 + tid;
      int bm = r >> 5;
      int b = bm / g.M;
      int n = g.idx[(size_t)bm * KN + (r & (KN - 1))];
      int nb = b * g.Ncur + n;
      grow[tid] = nb;
      nxs[tid][0] = g.xyz[(size_t)nb * 3 + 0] - g.ctr[(size_t)bm * 3 + 0];
      nxs[tid][1] = g.xyz[(size_t)nb * 3 + 1] - g.ctr[(size_t)bm * 3 + 1];
      nxs[tid][2] = g.xyz[(size_t)nb * 3 + 2] - g.ctr[(size_t)bm * 3 + 2];
    } else if (tid < 192) {
      int o = tid - 128;
      waxs[o][0] = g.W[(size_t)(bo0 + o) * g.wk + 0];
      waxs[o][1] = g.W[(size_t)(bo0 + o) * g.wk + 1];
      waxs[o][2] = g.W[(size_t)(bo0 + o) * g.wk + 2];
    }
    __syncthreads();
    // prefetch gathered Ga tile + Gm row into regs; latency hides under K-loop
#pragma unroll
    for (int p = 0; p < 4; ++p) {
      int i = tid + p * 256;
      int rl = i >> 3, sg = (i & 7) * 8;
      rGa[p] = *(const ushort8*)(g.Ga + (size_t)grow[rl] * g.O + bo0 + sg);
    }
    gmv = g.Gm[(size_t)((br0 >> 5) + (tid >> 6)) * g.O + bo0 + (tid & 63)];
  }

  f32x4 acc[2][4] = {};
  const int arow0 = (w * 16 + (lane & 15)) * BKP + (lane >> 4) * 8;
  const int arow1 = arow0 + 64 * BKP;
  const int sr = tid >> 2;          // staging row (0..63; +64 for 2nd half)
  const int sc8 = (tid & 3) * 8;    // staging k-offset
  const int wr = tid >> 2;
  const int wkb = (tid & 3) * 8;
  const float* wrow = WBF16 ? nullptr : (g.W + (size_t)(bo0 + wr) * g.wk + g.colOff);

  auto loadChunk = [&](int kk, ushort8& a0, ushort8& a1, ushort8& ww) {
    if constexpr (ABF16) {
      a0 = *(const ushort8*)(g.Ab + (size_t)(br0 + sr) * g.lda + kk + sc8);
      a1 = *(const ushort8*)(g.Ab + (size_t)(br0 + 64 + sr) * g.lda + kk + sc8);
    } else {
      const float* ap0 = g.Af + (size_t)(br0 + sr) * g.lda + kk + sc8;
      const float* ap1 = g.Af + (size_t)(br0 + 64 + sr) * g.lda + kk + sc8;
#pragma unroll
      for (int e = 0; e < 8; ++e) {
        float v0 = ap0[e], v1 = ap1[e];
        if constexpr (ABN) {
          float2 st = g.bnstA[kk + sc8 + e];
          v0 = fmaxf((v0 - st.x) * st.y, 0.f);
          v1 = fmaxf((v1 - st.x) * st.y, 0.f);
        }
        a0[e] = f2bu(v0); a1[e] = f2bu(v1);
      }
    }
    if constexpr (WBF16) {
      ww = *(const ushort8*)(g.Wb + (size_t)(bo0 + wr) * g.K + kk + wkb);
    } else {
#pragma unroll
      for (int e = 0; e < 8; ++e) ww[e] = f2bu(wrow[kk + wkb + e]);
    }
  };

  // ---- prologue: load chunk pair (k=0, k=BKM) into registers ----
  ushort8 rA0, rA1, rW, rB0, rB1, rWb;
  loadChunk(0, rA0, rA1, rW);
  loadChunk(BKM, rB0, rB1, rWb);

  for (int k0 = 0; k0 < g.K; k0 += 2 * BKM) {
    // ---- write both chunks to LDS ----
    *(ushort8*)((unsigned short*)As + sr * BKP + sc8) = rA0;
    *(ushort8*)((unsigned short*)As + (64 + sr) * BKP + sc8) = rA1;
    *(ushort8*)((unsigned short*)Ws + wr * BKP + wkb) = rW;
    *(ushort8*)((unsigned short*)As2 + sr * BKP + sc8) = rB0;
    *(ushort8*)((unsigned short*)As2 + (64 + sr) * BKP + sc8) = rB1;
    *(ushort8*)((unsigned short*)Ws2 + wr * BKP + wkb) = rWb;
    __syncthreads();
    // ---- issue next pair's loads (latency hidden under compute) ----
    ushort8 nA0, nA1, nW, nB0, nB1, nWb;
    const int k1 = k0 + 2 * BKM;
    if (k1 < g.K) {
      loadChunk(k1, nA0, nA1, nW);
      loadChunk(k1 + BKM, nB0, nB1, nWb);
    }
    // ---- compute: chunk a then chunk b (same order as sequential loop) ----
    {
      bf16x8 av0 = *(const bf16x8*)(As + arow0);
      bf16x8 av1 = *(const bf16x8*)(As + arow1);
#pragma unroll
      for (int nf = 0; nf < 4; ++nf) {
        bf16x8 bv = *(const bf16x8*)(Ws + (nf * 16 + (lane & 15)) * BKP + (lane >> 4) * 8);
        acc[0][nf] = __builtin_amdgcn_mfma_f32_16x16x32_bf16(av0, bv, acc[0][nf], 0, 0, 0);
        acc[1][nf] = __builtin_amdgcn_mfma_f32_16x16x32_bf16(av1, bv, acc[1][nf], 0, 0, 0);
      }
    }
    {
      bf16x8 av0 = *(const bf16x8*)(As2 + arow0);
      bf16x8 av1 = *(const bf16x8*)(As2 + arow1);
#pragma unroll
      for (int nf = 0; nf < 4; ++nf) {
        bf16x8 bv = *(const bf16x8*)(Ws2 + (nf * 16 + (lane & 15)) * BKP + (lane >> 4) * 8);
        acc[0][nf] = __builtin_amdgcn_mfma_f32_16x16x32_bf16(av0, bv, acc[0][nf], 0, 0, 0);
        acc[1][nf] = __builtin_amdgcn_mfma_f32_16x16x32_bf16(av1, bv, acc[1][nf], 0, 0, 0);
      }
    }
    __syncthreads();
    rA0 = nA0; rA1 = nA1; rW = nW; rB0 = nB0; rB1 = nB1; rWb = nWb;
  }

  const int col0 = lane & 15;
  unsigned short* GaS = (unsigned short*)smemraw;       // EP2: [128][68] bf16
  float* GmS = (float*)(smemraw + 17408);               // EP2: [4][64] f32
  float* red0 = (EP == 2) ? (float*)(smemraw + 18432) : (float*)smemraw;
  float* red1 = red0 + 256;

  if constexpr (EP == 2) {
    // write prefetched Ga tile + Gm rows to LDS (no global latency here)
#pragma unroll
    for (int p = 0; p < 4; ++p) {
      int i = tid + p * 256;
      int rl = i >> 3, sg = (i & 7) * 8;
      *(ushort8*)(GaS + rl * 68 + sg) = rGa[p];
    }
    GmS[tid] = gmv;
    __syncthreads();
  }

#pragma unroll
  for (int rf = 0; rf < 2; ++rf) {
    const int rbase = rf * 64 + w * 16 + (lane >> 4) * 4;
    if constexpr (EP == 0) {
#pragma unroll
      for (int nf = 0; nf < 4; ++nf) {
        int o = bo0 + nf * 16 + col0;
#pragma unroll
        for (int e = 0; e < 4; ++e)
          g.outf[(size_t)(br0 + rbase + e) * g.O + o] = acc[rf][nf][e];
      }
    }
    if constexpr (EP == 1) {
#pragma unroll
      for (int nf = 0; nf < 4; ++nf) {
        int o = bo0 + nf * 16 + col0;
        __hip_bfloat16* dst;
        int oc, ostr;
        if (g.outb2) {
          ostr = g.Oh;
          if (o >= g.Oh) { dst = g.outb2; oc = o - g.Oh; }
          else { dst = g.outb; oc = o; }
        } else {
          dst = g.outb; oc = o; ostr = g.O;
        }
#pragma unroll
        for (int e = 0; e < 4; ++e)
          dst[(size_t)(br0 + rbase + e) * ostr + oc] = __float2bfloat16(acc[rf][nf][e]);
      }
    }
    if constexpr (EP == 2 || EP == 3) {
      float vals[4][4];
#pragma unroll
      for (int nf = 0; nf < 4; ++nf) {
        int ol = nf * 16 + col0;
        int o = bo0 + ol;
#pragma unroll
        for (int e = 0; e < 4; ++e) {
          int rl = rbase + e;
          float v = acc[rf][nf][e];
          if constexpr (EP == 2) {
            v += b2f(GaS[rl * 68 + ol]) +
                 nxs[rl][0] * waxs[ol][0] + nxs[rl][1] * waxs[ol][1] +
                 nxs[rl][2] * waxs[ol][2] - GmS[((rl >> 5) << 6) + ol];
          }
          vals[nf][e] = v;
          if constexpr (EP == 2)
            g.outb[(size_t)(br0 + rl) * g.O + o] = __float2bfloat16(v);
          else
            g.outf[(size_t)(br0 + rl) * g.O + o] = v;
        }
      }
#pragma unroll
      for (int nf = 0; nf < 4; ++nf) {
        float s0 = vals[nf][0] + vals[nf][1] + vals[nf][2] + vals[nf][3];
        float s1 = vals[nf][0] * vals[nf][0] + vals[nf][1] * vals[nf][1] +
                   vals[nf][2] * vals[nf][2] + vals[nf][3] * vals[nf][3];
        s0 += __shfl_xor(s0, 16); s0 += __shfl_xor(s0, 32);
        s1 += __shfl_xor(s1, 16); s1 += __shfl_xor(s1, 32);
        if ((lane >> 4) == 0) {
          red0[w * 64 + nf * 16 + lane] = s0;
          red1[w * 64 + nf * 16 + lane] = s1;
        }
      }
      __syncthreads();
      if (tid < 64) {
        float t0 = red0[tid] + red0[64 + tid] + red0[128 + tid] + red0[192 + tid];
        float t1 = red1[tid] + red1[64 + tid] + red1[128 + tid] + red1[192 + tid];
        size_t base = ((size_t)(rt * 2 + rf) * g.numOt + ot) * 128;
        g.partial[base + tid] = t0;
        g.partial[base + 64 + tid] = t1;
      }
      __syncthreads();
    }
  }
}

// ================= fp combine: fp_pre = Gf[nbr] + nx.Wfx, + partials =================
__global__ __launch_bounds__(256) void combine_fp_kernel(
    const unsigned short* Gf, const float* Wf, int wk,
    const float* xyz, const float* ctr, const int* idx,
    __hip_bfloat16* fpout, float* partial, int numOt, int M, int Ncur, int O) {
  __shared__ float tile[64][68];
  __shared__ float nxs[64][3];
  __shared__ float wfx[64][3];
  __shared__ int grow[64];
  int tid = threadIdx.x;
  int rt = blockIdx.x, ot = blockIdx.y;
  int br0 = rt * 64, bo0 = ot * 64;
  if (tid < 64) {
    int r = br0 + tid;
    int bm = r >> 5;
    int b = bm / M;
    int n = idx[(size_t)bm * KN + (r & (KN - 1))];
    int nb = b * Ncur + n;
    grow[tid] = nb;
    nxs[tid][0] = xyz[(size_t)nb * 3 + 0] - ctr[(size_t)bm * 3 + 0];
    nxs[tid][1] = xyz[(size_t)nb * 3 + 1] - ctr[(size_t)bm * 3 + 1];
    nxs[tid][2] = xyz[(size_t)nb * 3 + 2] - ctr[(size_t)bm * 3 + 2];
  } else if (tid < 128) {
    int o = tid - 64;
    wfx[o][0] = Wf[(size_t)(bo0 + o) * wk + 0];
    wfx[o][1] = Wf[(size_t)(bo0 + o) * wk + 1];
    wfx[o][2] = Wf[(size_t)(bo0 + o) * wk + 2];
  }
  __syncthreads();
  int rr = tid >> 2, os = (tid & 3) * 16;
  const unsigned short* gr = Gf + (size_t)grow[rr] * O + bo0 + os;
  ushort8 v0 = *(const ushort8*)gr;
  ushort8 v1 = *(const ushort8*)(gr + 8);
  __hip_bfloat16* outp = fpout + (size_t)(br0 + rr) * O + bo0 + os;
  float nx0 = nxs[rr][0], nx1 = nxs[rr][1], nx2 = nxs[rr][2];
#pragma unroll
  for (int i = 0; i < 16; ++i) {
    float gv = b2f(i < 8 ? v0[i] : v1[i - 8]);
    int o = os + i;
    float val = gv + nx0 * wfx[o][0] + nx1 * wfx[o][1] + nx2 * wfx[o][2];
    tile[rr][o] = val;
    outp[i] = __float2bfloat16(val);
  }
  __syncthreads();
  if (tid < 64) {
    float s = 0.f, s2 = 0.f;
#pragma unroll 4
    for (int r2 = 0; r2 < 64; ++r2) {
      float v = tile[r2][tid];
      s += v; s2 += v * v;
    }
    size_t base = ((size_t)rt * numOt + ot) * 128;
    partial[base + tid] = s;
    partial[base + 64 + tid] = s2;
  }
}

// ================= fused bn+relu (in-place) + k-mean for fp buffer =================
// 256 threads = 4 bm-slabs per block (one per 64-lane group) for occupancy.
__global__ __launch_bounds__(256) void bn_fpmean_kernel(__hip_bfloat16* fp, const float2* stats2,
                                                        __hip_bfloat16* outm, int O) {
  int bm = blockIdx.x * 4 + (threadIdx.x >> 6);
  int o = blockIdx.y * 64 + (threadIdx.x & 63);
  float2 st = stats2[o];
  __hip_bfloat16* p = fp + (size_t)bm * KN * O + o;
  float s = 0.f;
#pragma unroll
  for (int kk = 0; kk < KN; ++kk) {
    float v = __bfloat162float(p[(size_t)kk * O]);
    float y = fmaxf((v - st.x) * st.y, 0.f);
    __hip_bfloat16 yb = __float2bfloat16(y);
    p[(size_t)kk * O] = yb;
    s += __bfloat162float(yb);
  }
  outm[(size_t)bm * O + o] = __float2bfloat16(s * (1.f / KN));
}

// ================= apply: bn+relu+softmax+weighted sum =================
// 256 threads = 4 bm per block (one per 64-lane group) for occupancy.
__global__ __launch_bounds__(256) void apply_lite_kernel(const __hip_bfloat16* alpha,
                                                         const __hip_bfloat16* fp,
                                                         const float2* stats2, float* fout, int O) {
  int bm = blockIdx.x * 4 + (threadIdx.x >> 6);
  int o = blockIdx.y * 64 + (threadIdx.x & 63);
  float2 st = stats2[o];
  size_t base = (size_t)bm * KN * O + o;
  float a[KN];
  float mx = -3.4e38f;
#pragma unroll
  for (int kk = 0; kk < KN; ++kk) {
    float v = fmaxf((__bfloat162float(alpha[base + (size_t)kk * O]) - st.x) * st.y, 0.f);
    a[kk] = v; mx = fmaxf(mx, v);
  }
  float s = 0.f;
#pragma unroll
  for (int kk = 0; kk < KN; ++kk) { float e = expf(a[kk] - mx); a[kk] = e; s += e; }
  float acc = 0.f;
#pragma unroll
  for (int kk = 0; kk < KN; ++kk) acc += a[kk] * __bfloat162float(fp[base + (size_t)kk * O]);
  fout[(size_t)bm * O + o] = acc / s;
}

// ================= fp32 dense GEMM (SPFE / head2) =================
// R29: ABN fuses bn+relu into the A-staging (bit-identical to the standalone pass).
struct GemmArgs {
  const float* A; const float* W; const float* bias;
  float* out; __hip_bfloat16* outb;
  float* partial; const float2* stats2; float* fout;
  const __hip_bfloat16* fpb; const float* fpmean;
  const float* xyz; const float* feat; const float* ctr; const int* idx; const float* bmean;
  int R, K, O, numOt, M, Cf, Of, Ncur;
};

template <int EMODE, int MODE, bool ABN>
__global__ __launch_bounds__(256) void gemm_dense(GemmArgs g) {
  __shared__ float smem[2 * BKK * ASTR];
  float* As = smem;
  float* Ws = smem + BKK * ASTR;
  const int tid = threadIdx.x;
  const int tr = tid >> 4, tc = tid & 15;
  const int rt = blockIdx.x, ot = blockIdx.y;
  const int br0 = rt * BR, bo0 = ot * BO;
  float acc[4][4] = {};
  for (int k0 = 0; k0 < g.K; k0 += BKK) {
    for (int i = tid; i < BR * BKK; i += 256) {
      int rr = i >> 4, cc = i & 15;
      int c = k0 + cc;
      float v = 0.f;
      if (c < g.K) {
        if constexpr (MODE == 0) {
          v = g.A[(size_t)(br0 + rr) * g.K + c];
          if constexpr (ABN) {
            float2 st = g.stats2[c];
            v = fmaxf((v - st.x) * st.y, 0.f);
          }
        } else {
          int r = br0 + rr;
          int b = r / g.Ncur, n = r - b * g.Ncur;
          if (c < 3) v = g.xyz[((size_t)b * g.Ncur + n) * 3 + c];
          else if (c < 6) v = g.xyz[((size_t)b * g.Ncur + n) * 3 + (c - 3)] - g.bmean[b * 3 + (c - 3)];
        }
      }
      As[cc * ASTR + rr] = v;
    }
    for (int i = tid; i < BO * BKK; i += 256) {
      int oo = i >> 4, cc = i & 15;
      int o = bo0 + oo, c = k0 + cc;
      Ws[cc * ASTR + oo] = (o < g.O && c < g.K) ? g.W[(size_t)o * g.K + c] : 0.f;
    }
    __syncthreads();
#pragma unroll
    for (int kk = 0; kk < BKK; ++kk) {
      float a0[4], w0[4];
#pragma unroll
      for (int i = 0; i < 4; ++i) a0[i] = As[kk * ASTR + tr * 4 + i];
#pragma unroll
      for (int j = 0; j < 4; ++j) w0[j] = Ws[kk * ASTR + tc * 4 + j];
#pragma unroll
      for (int i = 0; i < 4; ++i)
#pragma unroll
        for (int j = 0; j < 4; ++j) acc[i][j] += a0[i] * w0[j];
    }
    __syncthreads();
  }
#pragma unroll
  for (int i = 0; i < 4; ++i) {
    int r = br0 + tr * 4 + i;
    if (r >= g.R) continue;
#pragma unroll
    for (int j = 0; j < 4; ++j) {
      int o = bo0 + tc * 4 + j;
      if (o >= g.O) continue;
      float v = acc[i][j];
      if (EMODE == 0 && g.bias) v += g.bias[o];
      g.out[(size_t)r * g.O + o] = v;
    }
  }
  if constexpr (EMODE == 1) {
    float* red0 = smem;
    float* red1 = smem + 1024;
#pragma unroll
    for (int j = 0; j < 4; ++j) {
      float s0 = 0.f, s1 = 0.f;
#pragma unroll
      for (int i = 0; i < 4; ++i) { float v = acc[i][j]; s0 += v; s1 += v * v; }
      red0[tr * 64 + tc * 4 + j] = s0;
      red1[tr * 64 + tc * 4 + j] = s1;
    }
    __syncthreads();
    for (int st = 8; st >= 1; st >>= 1) {
      if (tr < st) {
#pragma unroll
        for (int j = 0; j < 4; ++j) {
          int cix = tc * 4 + j;
          red0[tr * 64 + cix] += red0[(tr + st) * 64 + cix];
          red1[tr * 64 + cix] += red1[(tr + st) * 64 + cix];
        }
      }
      __syncthreads();
    }
    if (tr == 0) {
      size_t base = ((size_t)rt * g.numOt + ot) * 128;
#pragma unroll
      for (int j = 0; j < 4; ++j) {
        int cix = tc * 4 + j;
        g.partial[base + cix] = red0[cix];
        g.partial[base + 64 + cix] = red1[cix];
      }
    }
  }
}

// ================= stats / bn =================
__global__ void reduce_finalize_kernel(const float* partial, float2* stats2,
                                       int Rt, int numOt, int R, int O) {
  int o = blockIdx.x;
  int ot = o >> 6, oo = o & 63;
  int tid = threadIdx.x;
  double s = 0.0, s2 = 0.0;
  for (int rtt = tid; rtt < Rt; rtt += 256) {
    const float* p = partial + ((size_t)rtt * numOt + ot) * 128;
    s += (double)p[oo];
    s2 += (double)p[64 + oo];
  }
  __shared__ double r0[256], r1[256];
  r0[tid] = s; r1[tid] = s2;
  __syncthreads();
  for (int st = 128; st > 0; st >>= 1) {
    if (tid < st) { r0[tid] += r0[tid + st]; r1[tid] += r1[tid + st]; }
    __syncthreads();
  }
  if (tid == 0) {
    double mu = r0[0] / R;
    double var = r1[0] / R - mu * mu;
    stats2[o] = make_float2((float)mu, 1.f / sqrtf((float)var + EPSV));
  }
}

template <bool BF16>
__global__ void bn_apply_relu_kernel(void* xv, const float2* stats2, long long tot, int C) {
  float* xf = (float*)xv;
  __hip_bfloat16* xb = (__hip_bfloat16*)xv;
  for (long long gidx = (long long)blockIdx.x * blockDim.x + threadIdx.x; gidx < tot;
       gidx += (long long)gridDim.x * blockDim.x) {
    int c = (int)(gidx % C);
    float2 st = stats2[c];
    float v = BF16 ? __bfloat162float(xb[gidx]) : xf[gidx];
    float y = fmaxf((v - st.x) * st.y, 0.f);
    if (BF16) xb[gidx] = __float2bfloat16(y);
    else xf[gidx] = y;
  }
}

// ================= misc =================
__global__ void mean_xyz_kernel(const float* xyz, float* bmean, int N) {
  int b = blockIdx.x, tid = threadIdx.x;
  __shared__ float s[3][256];
  float sx = 0, sy = 0, sz = 0;
  for (int n = tid; n < N; n += 256) {
    const float* p = xyz + ((size_t)b * N + n) * 3;
    sx += p[0]; sy += p[1]; sz += p[2];
  }
  s[0][tid] = sx; s[1][tid] = sy; s[2][tid] = sz;
  __syncthreads();
  for (int st = 128; st > 0; st >>= 1) {
    if (tid < st) {
      s[0][tid] += s[0][tid + st];
      s[1][tid] += s[1][tid + st];
      s[2][tid] += s[2][tid + st];
    }
    __syncthreads();
  }
  if (tid < 3) bmean[b * 3 + tid] = s[tid][0] / (float)N;
}

__global__ void centers_kernel(const float* xyz, float* ctr, int B, int N, int M) {
  int g = blockIdx.x * blockDim.x + threadIdx.x;
  if (g >= B * M) return;
  int b = g / M, m = g % M;
  float delta = (float)(N - 1) / (float)(M - 1);
  int n = (int)((float)m * delta);
  if (n > N - 1) n = N - 1;
  ctr[(size_t)g * 3 + 0] = xyz[((size_t)b * N + n) * 3 + 0];
  ctr[(size_t)g * 3 + 1] = xyz[((size_t)b * N + n) * 3 + 1];
  ctr[(size_t)g * 3 + 2] = xyz[((size_t)b * N + n) * 3 + 2];
}

// KNN with per-lane sorted top-4 head lists (verified R15; 16-wave blocks verified R22)
__global__ __launch_bounds__(1024) void knn_heads_kernel(const float* xyz, const float* ctr,
                                                         int* idx_out, int B, int N, int M) {
  extern __shared__ float sm[];
  const int pitch = N + (N >> 6);
  float* xs = sm;
  float* ys = sm + pitch;
  float* zs = sm + 2 * pitch;
  const int b = blockIdx.y;
  const int tid = threadIdx.x;
  const float* xb = xyz + (size_t)b * N * 3;
  for (int i = tid; i < N; i += blockDim.x) {
    int pi = i + (i >> 6);
    xs[pi] = xb[i * 3 + 0];
    ys[pi] = xb[i * 3 + 1];
    zs[pi] = xb[i * 3 + 2];
  }
  __syncthreads();
  const int w = tid >> 6, lane = tid & 63;
  const int wpb = blockDim.x >> 6;
  const int m = blockIdx.x * wpb + w;
  if (m >= M) return;
  const int bm = b * M + m;
  const float cx = ctr[(size_t)bm * 3], cy = ctr[(size_t)bm * 3 + 1], cz = ctr[(size_t)bm * 3 + 2];
  const float cc = cx * cx + cy * cy + cz * cz;
  const int npl = N >> 6;
  const int shift = 31 - __clz(npl);
  const int base = lane * npl;
  const int pb = base + (base >> 6);
  const float INF = 3.4e38f;
  const int IMAX = 0x7fffffff;

  float a0 = INF, a1 = INF, a2 = INF, a3 = INF;
  int i0 = IMAX, i1 = IMAX, i2 = IMAX, i3 = IMAX;
  for (int j = 0; j < npl; ++j) {
    float x = xs[pb + j], y = ys[pb + j], z = zs[pb + j];
    float d2 = cc + (x * x + y * y + z * z) - 2.f * (cx * x + cy * y + cz * z);
    int gj = base + j;
    bool lt0 = (d2 < a0) || (d2 == a0 && gj < i0);
    bool lt1 = (d2 < a1) || (d2 == a1 && gj < i1);
    bool lt2 = (d2 < a2) || (d2 == a2 && gj < i2);
    bool lt3 = (d2 < a3) || (d2 == a3 && gj < i3);
    float na3 = lt2 ? a2 : (lt3 ? d2 : a3); int ni3 = lt2 ? i2 : (lt3 ? gj : i3);
    float na2 = lt1 ? a1 : (lt2 ? d2 : a2); int ni2 = lt1 ? i1 : (lt2 ? gj : i2);
    float na1 = lt0 ? a0 : (lt1 ? d2 : a1); int ni1 = lt0 ? i0 : (lt1 ? gj : i1);
    float na0 = lt0 ? d2 : a0;              int ni0 = lt0 ? gj : i0;
    a0 = na0; a1 = na1; a2 = na2; a3 = na3;
    i0 = ni0; i1 = ni1; i2 = ni2; i3 = ni3;
  }

  unsigned int rmlo = 0u, rmhi = 0u;
  int remaining = npl;

  for (int sel = 0; sel < KN; ++sel) {
    float d = a0;
    int ii = i0;
#pragma unroll
    for (int off = 1; off < 64; off <<= 1) {
      float od = __shfl_xor(d, off);
      int oi = __shfl_xor(ii, off);
      if (od < d || (od == d && oi < ii)) { d = od; ii = oi; }
    }
    if (lane == 0) idx_out[(size_t)bm * KN + sel] = ii;
    const int owner = ii >> shift;
    if (lane == owner) {
      int jin = ii - (owner << shift);
      if (jin < 32) rmlo |= 1u << jin;
      else rmhi |= 1u << (jin - 32);
      remaining--;
      a0 = a1; i0 = i1; a1 = a2; i1 = i2; a2 = a3; i2 = i3;
      a3 = INF; i3 = IMAX;
    }
    if (sel == KN - 1) break;
    float h = __shfl(a0, owner);
    int remo = __shfl(remaining, owner);
    if (h >= INF && remo > 0) {
      unsigned int olo = __shfl(rmlo, owner);
      unsigned int ohi = __shfl(rmhi, owner);
      const int obase = owner << shift;
      const int opb = obase + (obase >> 6);
      float c0 = INF, c1 = INF, c2 = INF, c3 = INF;
      int jc0 = IMAX, jc1 = IMAX, jc2 = IMAX, jc3 = IMAX;
      if (lane < npl) {
        bool rem = (lane < 32) ? ((olo >> lane) & 1u) : ((ohi >> (lane - 32)) & 1u);
        if (!rem) {
          float x = xs[opb + lane], y = ys[opb + lane], z = zs[opb + lane];
          c0 = cc + (x * x + y * y + z * z) - 2.f * (cx * x + cy * y + cz * z);
          jc0 = obase + lane;
        }
      }
#pragma unroll
      for (int off = 1; off < 64; off <<= 1) {
        float b0v = __shfl_xor(c0, off), b1v = __shfl_xor(c1, off);
        float b2v = __shfl_xor(c2, off), b3v = __shfl_xor(c3, off);
        int d0v = __shfl_xor(jc0, off), d1v = __shfl_xor(jc1, off);
        int d2v = __shfl_xor(jc2, off), d3v = __shfl_xor(jc3, off);
        bool t1 = (c0 < b0v) || (c0 == b0v && jc0 < d0v);
        float o0 = t1 ? c0 : b0v; int p0 = t1 ? jc0 : d0v;
        float A0 = t1 ? c1 : c0, A1 = t1 ? c2 : c1, A2 = t1 ? c3 : c2;
        int IA0 = t1 ? jc1 : jc0, IA1 = t1 ? jc2 : jc1, IA2 = t1 ? jc3 : jc2;
        float B0 = t1 ? b0v : b1v, B1 = t1 ? b1v : b2v, B2 = t1 ? b2v : b3v;
        int IB0 = t1 ? d0v : d1v, IB1 = t1 ? d1v : d2v, IB2 = t1 ? d2v : d3v;
        bool t2 = (A0 < B0) || (A0 == B0 && IA0 < IB0);
        float o1 = t2 ? A0 : B0; int p1 = t2 ? IA0 : IB0;
        float A0b = t2 ? A1 : A0, A1b = t2 ? A2 : A1;
        int IA0b = t2 ? IA1 : IA0, IA1b = t2 ? IA2 : IA1;
        float B0b = t2 ? B0 : B1, B1b = t2 ? B1 : B2;
        int IB0b = t2 ? IB0 : IB1, IB1b = t2 ? IB1 : IB2;
        bool t3 = (A0b < B0b) || (A0b == B0b && IA0b < IB0b);
        float o2 = t3 ? A0b : B0b; int p2 = t3 ? IA0b : IB0b;
        float A0c = t3 ? A1b : A0b; int IA0c = t3 ? IA1b : IA0b;
        float B0c = t3 ? B0b : B1b; int IB0c = t3 ? IB0b : IB1b;
        bool t4 = (A0c < B0c) || (A0c == B0c && IA0c < IB0c);
        float o3 = t4 ? A0c : B0c; int p3 = t4 ? IA0c : IB0c;
        c0 = o0; c1 = o1; c2 = o2; c3 = o3;
        jc0 = p0; jc1 = p1; jc2 = p2; jc3 = p3;
      }
      if (lane == owner) {
        a0 = c0; a1 = c1; a2 = c2; a3 = c3;
        i0 = jc0; i1 = jc1; i2 = jc2; i3 = jc3;
      }
    }
  }
}

// interp3, 4 scanners per low-res point (verified R14)
__global__ __launch_bounds__(256) void interp3_par_kernel(const float* xl, const float* xh,
                                                          int* idx3, float* w3, int Nl, int Nh) {
  extern __shared__ float sm[];
  float* xs = sm;
  float* ys = sm + Nh;
  float* zs = sm + 2 * Nh;
  const int b = blockIdx.y;
  const int tid = threadIdx.x;
  const float* xb = xh + (size_t)b * Nh * 3;
  for (int i = tid; i < Nh; i += 256) {
    xs[i] = xb[i * 3 + 0];
    ys[i] = xb[i * 3 + 1];
    zs[i] = xb[i * 3 + 2];
  }
  __syncthreads();
  const int pt = tid >> 2, sc = tid & 3;
  const int l = blockIdx.x * 64 + pt;
  if (l >= Nl) return;
  const size_t g = (size_t)b * Nl + l;
  const float px = xl[g * 3], py = xl[g * 3 + 1], pz = xl[g * 3 + 2];
  const float pp = px * px + py * py + pz * pz;
  const int chunk = Nh >> 2;
  const int j0 = sc * chunk, j1 = j0 + chunk;
  float a0 = 3.4e38f, a1 = 3.4e38f, a2 = 3.4e38f;
  int i0 = 0x7fffffff, i1 = 0x7fffffff, i2 = 0x7fffffff;
  for (int j = j0; j < j1; ++j) {
    float x = xs[j], y = ys[j], z = zs[j];
    float d2 = (pp + (x * x + y * y + z * z)) - 2.f * (px * x + py * y + pz * z);
    if (d2 < a0) {
      a2 = a1; i2 = i1; a1 = a0; i1 = i0; a0 = d2; i0 = j;
    } else if (d2 < a1) {
      a2 = a1; i2 = i1; a1 = d2; i1 = j;
    } else if (d2 < a2) {
      a2 = d2; i2 = j;
    }
  }
#pragma unroll
  for (int off = 1; off < 4; off <<= 1) {
    float b0 = __shfl_xor(a0, off), b1 = __shfl_xor(a1, off), b2 = __shfl_xor(a2, off);
    int c0 = __shfl_xor(i0, off), c1 = __shfl_xor(i1, off), c2 = __shfl_xor(i2, off);
    bool t = (a0 < b0) || (a0 == b0 && i0 < c0);
    float o0 = t ? a0 : b0; int oi0 = t ? i0 : c0;
    float na0 = t ? a1 : a0, na1 = t ? a2 : a1;
    int nia0 = t ? i1 : i0, nia1 = t ? i2 : i1;
    float nb0 = t ? b0 : b1, nb1 = t ? b1 : b2;
    int nib0 = t ? c0 : c1, nib1 = t ? c1 : c2;
    bool t2 = (na0 < nb0) || (na0 == nb0 && nia0 < nib0);
    float o1 = t2 ? na0 : nb0; int oi1 = t2 ? nia0 : nib0;
    float ma0 = t2 ? na1 : na0; int mia0 = t2 ? nia1 : nia0;
    float mb0 = t2 ? nb0 : nb1; int mib0 = t2 ? nib0 : nib1;
    bool t3 = (ma0 < mb0) || (ma0 == mb0 && mia0 < mib0);
    float o2 = t3 ? ma0 : mb0; int oi2 = t3 ? mia0 : mib0;
    a0 = o0; a1 = o1; a2 = o2; i0 = oi0; i1 = oi1; i2 = oi2;
  }
  if (sc == 0) {
    float d0 = fmaxf(sqrtf(fmaxf(a0, 0.f)), 1e-8f);
    float d1 = fmaxf(sqrtf(fmaxf(a1, 0.f)), 1e-8f);
    float d2_ = fmaxf(sqrtf(fmaxf(a2, 0.f)), 1e-8f);
    float w0 = 1.f / d0, w1 = 1.f / d1, w2 = 1.f / d2_;
    float s = w0 + w1 + w2;
    idx3[g * 3 + 0] = i0;
    idx3[g * 3 + 1] = i1;
    idx3[g * 3 + 2] = i2;
    w3[g * 3 + 0] = w0 / s;
    w3[g * 3 + 1] = w1 / s;
    w3[g * 3 + 2] = w2 / s;
  }
}

__global__ void buildx_kernel(const float* fh, const float* fl, const int* idx3, const float* w3,
                              float* xout, int B, int Nl, int Nh, int Ch, int Cl) {
  int Cx = Ch + Cl;
  size_t tot = (size_t)B * Nl * Cx;
  for (size_t g = (size_t)blockIdx.x * blockDim.x + threadIdx.x; g < tot;
       g += (size_t)gridDim.x * blockDim.x) {
    int r = (int)(g / Cx), c = (int)(g % Cx);
    int b = r / Nl;
    if (c < Ch) {
      float s = 0.f;
      for (int j = 0; j < 3; ++j) {
        int n = idx3[(size_t)r * 3 + j];
        s += w3[(size_t)r * 3 + j] * fh[((size_t)b * Nh + n) * Ch + c];
      }
      xout[g] = s;
    } else {
      xout[g] = fl[(size_t)r * Cl + (c - Ch)];
    }
  }
}

// ================= host =================
extern "C" void kernel_launch(void* const* d_in, const int* in_sizes, int n_in,
                              void* d_out, int out_size, void* d_ws, size_t ws_size,
                              hipStream_t stream) {
  const int B = 8, N = 4096;
  const float* X = (const float*)d_in[0];
  const float* W_spfe1 = (const float*)d_in[1];
  const float* W_spfe2 = (const float*)d_in[3];
  const float* Wf1 = (const float*)d_in[5];
  const float* Wa1 = (const float*)d_in[7];
  const float* Wf2 = (const float*)d_in[9];
  const float* Wa2 = (const float*)d_in[11];
  const float* Wf3 = (const float*)d_in[13];
  const float* Wa3 = (const float*)d_in[15];
  const float* Wfp3 = (const float*)d_in[17];
  const float* Wfp2 = (const float*)d_in[19];
  const float* Wfp1 = (const float*)d_in[21];
  const float* Wh1 = (const float*)d_in[23];
  const float* Wh2 = (const float*)d_in[25];
  const float* bh2 = (const float*)d_in[26];
  float* out = (float*)d_out;

  char* wp = (char*)d_ws;
  auto alloc = [&](size_t bytes) -> void* {
    void* p = (void*)wp;
    wp += (bytes + 255) & ~(size_t)255;
    return p;
  };
  float2* stats2 = (float2*)alloc(512 * sizeof(float2) * 2);
  float* partial = (float*)alloc((size_t)8192 * 128 * 4);
  float* bmean = (float*)alloc(B * 3 * sizeof(float));
  float* f0 = (float*)alloc((size_t)B * N * 64 * 4);
  float* xyz1 = (float*)alloc((size_t)B * 1024 * 3 * 4);
  float* xyz2 = (float*)alloc((size_t)B * 512 * 3 * 4);
  float* xyz3 = (float*)alloc((size_t)B * 256 * 3 * 4);
  float* f1 = (float*)alloc((size_t)B * 1024 * 128 * 4);
  float* f2 = (float*)alloc((size_t)B * 512 * 256 * 4);
  float* f3 = (float*)alloc((size_t)B * 256 * 512 * 4);
  float* fpmean = (float*)alloc((size_t)B * 1024 * 128 * 4);
  __hip_bfloat16* fpmeanb = (__hip_bfloat16*)alloc((size_t)B * 1024 * 128 * 2);
  int* idxb = (int*)alloc((size_t)B * 1024 * KN * 4);
  int* idx3 = (int*)alloc((size_t)B * 4096 * 3 * 4);
  float* w3 = (float*)alloc((size_t)B * 4096 * 3 * 4);
  void* BIG = alloc((size_t)33554432 * 2);  // 64 MB: fp bf16 / f32 scratch
  size_t fup_off = (size_t)(wp - (char*)d_ws);
  float* fup2 = (float*)alloc((size_t)B * 512 * 256 * 4);
  float* fup1 = (float*)alloc((size_t)B * 1024 * 128 * 4);
  float* fup0 = (float*)alloc((size_t)B * 4096 * 128 * 4);
  // alpha aliases the fup region (disjoint lifetimes), 64 MB
  __hip_bfloat16* alphaBuf_all = (__hip_bfloat16*)((char*)d_ws + fup_off);
  size_t alpha_end = fup_off + (size_t)67108864;
  char* wp2 = (char*)d_ws + alpha_end;
  if (wp2 < wp) wp2 = wp;
  __hip_bfloat16* Gfb = (__hip_bfloat16*)wp2; wp2 += (size_t)8 * 1024 * 1024;
  __hip_bfloat16* Gab = (__hip_bfloat16*)wp2; wp2 += (size_t)8 * 1024 * 1024;
  float* Gm = (float*)wp2; wp2 += (size_t)4 * 1024 * 1024;
  __hip_bfloat16* Wbuf = (__hip_bfloat16*)wp2; wp2 += (size_t)2 * 1024 * 1024;  // bf16 W repack

  auto run_stats = [&](int R, int O) {
    reduce_finalize_kernel<<<O, 256, 0, stream>>>(partial, stats2, R / 64, O / 64, R, O);
  };
  auto run_bn = [&](void* x, int R, int C, bool bf) {
    long long tot = (long long)R * C;
    int blocks = (int)((tot + 255) / 256);
    if (blocks > 4096) blocks = 4096;
    if (bf) bn_apply_relu_kernel<true><<<blocks, 256, 0, stream>>>(x, stats2, tot, C);
    else bn_apply_relu_kernel<false><<<blocks, 256, 0, stream>>>(x, stats2, tot, C);
  };
  auto run_knn = [&](const float* xyz_in, const float* ctr, int Nc, int M) {
    int pitch = Nc + (Nc >> 6);
    size_t sm = (size_t)3 * pitch * 4;
    int wpb = ((M % 16) == 0) ? 16 : 4;
    knn_heads_kernel<<<dim3(M / wpb, B), wpb * 64, sm, stream>>>(xyz_in, ctr, idxb, B, Nc, M);
  };
  auto run_convw = [&](const float* W, int wk, int colOff, int O, int K, __hip_bfloat16* dst) {
    long long tot = (long long)O * K;
    convw_kernel<<<(int)((tot + 255) / 256), 256, 0, stream>>>(W, dst, wk, colOff, tot, K);
  };

  // ---- SPFE (fp32, small K) ----
  mean_xyz_kernel<<<B, 256, 0, stream>>>(X, bmean, N);
  float* hbuf = (float*)BIG;
  {
    GemmArgs g{};
    g.W = W_spfe1; g.out = hbuf; g.partial = partial;
    g.R = B * N; g.K = 9; g.O = 64; g.numOt = 1;
    g.xyz = X; g.bmean = bmean; g.Ncur = N;
    gemm_dense<1, 3, false><<<dim3(g.R / 64, 1), 256, 0, stream>>>(g);
    run_stats(g.R, g.O);
    // bn(hbuf) fused into SPFE2's A-staging (bit-identical)
  }
  {
    GemmArgs g{};
    g.A = hbuf; g.W = W_spfe2; g.out = f0; g.partial = partial;
    g.stats2 = stats2;
    g.R = B * N; g.K = 64; g.O = 64; g.numOt = 1;
    gemm_dense<1, 0, true><<<dim3(g.R / 64, 1), 256, 0, stream>>>(g);
    run_stats(g.R, g.O); run_bn(f0, g.R, g.O, false);
  }

  // ---- SA path (dense decomposed, pipelined GEMM, bf16-W, fused bn+fpmean) ----
  auto sa = [&](const float* xyz_in, const float* feat_in, int Nc, int M, int Cf, int Of,
                const float* Wf, const float* Wa, float* xyz_out, float* f_out) {
    int BM = B * M, R = BM * KN, NR = B * Nc;
    int wkF = 3 + Cf, wkA = 3 + Cf + Of;
    centers_kernel<<<ceil_div(BM, 256), 256, 0, stream>>>(xyz_in, xyz_out, B, Nc, M);
    run_knn(xyz_in, xyz_out, Nc, M);
    __hip_bfloat16* fpbuf = (__hip_bfloat16*)BIG;
    {  // [Gf | Ga] = feat . [Wf[:,3:3+Cf] ; Wa[:,3:3+Cf]]  (fused: one A pass)
      run_convw(Wf, wkF, 3, Of, Cf, Wbuf);
      run_convw(Wa, wkA, 3, Of, Cf, Wbuf + (size_t)Of * Cf);
      MdArgs m{}; m.Af = feat_in; m.lda = Cf;
      m.Wb = (const unsigned short*)Wbuf;
      m.R = NR; m.K = Cf; m.O = 2 * Of; m.Oh = Of;
      m.outb = Gfb; m.outb2 = Gab; m.numOt = (2 * Of) / 64;
      gemm_mdw<1, false, true, false><<<dim3(((2 * Of) / 64) * (NR / 128)), 256, 0, stream>>>(m);
    }
    combine_fp_kernel<<<dim3(R / 64, Of / 64), 256, 0, stream>>>(
        (const unsigned short*)Gfb, Wf, wkF, xyz_in, xyz_out, idxb, fpbuf,
        partial, Of / 64, M, Nc, Of);
    run_stats(R, Of);
    bn_fpmean_kernel<<<dim3(BM / 4, Of / 64), 256, 0, stream>>>(fpbuf, stats2, fpmeanb, Of);
    // WaP repack shared by Gm and alpha
    run_convw(Wa, wkA, 3 + Cf, Of, Of, Wbuf);
    {  // Gm = fpmean . Wa[:,3+Cf:]
      MdArgs m{}; m.Ab = (const unsigned short*)fpmeanb; m.lda = Of; m.W = Wa; m.wk = wkA;
      m.colOff = 3 + Cf; m.Wb = (const unsigned short*)Wbuf;
      m.R = BM; m.K = Of; m.O = Of; m.outf = Gm; m.numOt = Of / 64;
      gemm_mdw<0, true, true, false><<<dim3((Of / 64) * (BM / 128)), 256, 0, stream>>>(m);
    }
    {  // alpha = fp . Wa_p + Ga[nbr] + nx.Wa_x - Gm[bm]  (+ partials)
      MdArgs m{}; m.Ab = (const unsigned short*)fpbuf; m.lda = Of; m.W = Wa; m.wk = wkA;
      m.colOff = 3 + Cf; m.Wb = (const unsigned short*)Wbuf;
      m.R = R; m.K = Of; m.O = Of;
      m.outb = alphaBuf_all; m.partial = partial; m.numOt = Of / 64;
      m.Ga = (const unsigned short*)Gab; m.Gm = Gm;
      m.xyz = xyz_in; m.ctr = xyz_out; m.idx = idxb; m.M = M; m.Ncur = Nc;
      gemm_mdw<2, true, true, false><<<dim3((Of / 64) * (R / 128)), 256, 0, stream>>>(m);
    }
    run_stats(R, Of);
    apply_lite_kernel<<<dim3(BM / 4, Of / 64), 256, 0, stream>>>(alphaBuf_all, fpbuf, stats2, f_out, Of);
  };

  sa(X, f0, 4096, 1024, 64, 128, Wf1, Wa1, xyz1, f1);
  sa(xyz1, f1, 1024, 512, 128, 256, Wf2, Wa2, xyz2, f2);
  sa(xyz2, f2, 512, 256, 256, 512, Wf3, Wa3, xyz3, f3);

  // ---- FP layers (bf16 MFMA wide, EP3, bf16-W) ----
  // doBn=false leaves the raw output + stats2 for a fused-bn consumer.
  auto fpl = [&](const float* xl, const float* xh, const float* fl, const float* fh,
                 int Nl, int Nh, int Cl, int Ch, const float* W, float* f_up, int O, bool doBn) {
    size_t smI = (size_t)3 * Nh * 4;
    interp3_par_kernel<<<dim3(ceil_div(Nl, 64), B), 256, smI, stream>>>(xl, xh, idx3, w3, Nl, Nh);
    float* xbuf = (float*)BIG;
    int Cx = Ch + Cl;
    size_t tot = (size_t)B * Nl * Cx;
    int blocks = (int)((tot + 255) / 256);
    if (blocks > 4096) blocks = 4096;
    buildx_kernel<<<blocks, 256, 0, stream>>>(fh, fl, idx3, w3, xbuf, B, Nl, Nh, Ch, Cl);
    run_convw(W, Cx, 0, O, Cx, Wbuf);
    MdArgs m{};
    m.Af = xbuf; m.lda = Cx; m.W = W; m.wk = Cx; m.colOff = 0;
    m.R = B * Nl; m.K = Cx; m.O = O;
    m.Wb = (const unsigned short*)Wbuf;
    m.outf = f_up; m.partial = partial; m.numOt = O / 64;
    gemm_mdw<3, false, true, false><<<dim3((O / 64) * (m.R / 128)), 256, 0, stream>>>(m);
    run_stats(m.R, O);
    if (doBn) run_bn(f_up, m.R, O, false);
  };

  fpl(xyz2, xyz3, f2, f3, 512, 256, 256, 512, Wfp3, fup2, 256, true);
  fpl(xyz1, xyz2, f1, fup2, 1024, 512, 128, 256, Wfp2, fup1, 128, true);
  fpl(X, xyz1, f0, fup1, 4096, 1024, 64, 128, Wfp1, fup0, 128, false);  // bn fused into head

  // ---- head ----
  float* hh = (float*)BIG;
  {
    run_convw(Wh1, 128, 0, 128, 128, Wbuf);
    MdArgs m{};
    m.Af = fup0; m.lda = 128; m.W = Wh1; m.wk = 128; m.colOff = 0;
    m.Wb = (const unsigned short*)Wbuf;
    m.bnstA = stats2;   // fup0 stats (from fpl above) applied during A-staging
    m.R = B * N; m.K = 128; m.O = 128;
    m.outf = hh; m.partial = partial; m.numOt = 2;
    gemm_mdw<3, false, true, true><<<dim3(2 * (m.R / 128)), 256, 0, stream>>>(m);
    run_stats(m.R, m.O);
    // bn(hh) fused into head2's A-staging (bit-identical)
  }
  {
    GemmArgs g{};
    g.A = hh; g.W = Wh2; g.bias = bh2; g.out = out;
    g.stats2 = stats2;
    g.R = B * N; g.K = 128; g.O = 50; g.numOt = 1;
    gemm_dense<0, 0, true><<<dim3(g.R / 64, 1), 256, 0, stream>>>(g);
  }
}